// Round 5
// baseline (23119.315 us; speedup 1.0000x reference)
//
#include <hip/hip_runtime.h>
#include <math.h>

// Problem constants
#define BB   64
#define SS   256
#define ED   300
#define HH   512
#define G3   1536   // 3*H (one direction)
#define ATT_ 256
#define BS_  16384  // BB*SS

// ---------------------------------------------------------------------------
// K1: embedding gather + max-norm renorm.  one block per (b,s) row, 128 thr
// ---------------------------------------------------------------------------
__global__ void k_embed(const int* __restrict__ x, const float* __restrict__ emb,
                        float* __restrict__ e) {
    int row = blockIdx.x;
    int tok = x[row];
    const float* src = emb + (size_t)tok * ED;
    float* dst = e + (size_t)row * ED;
    int tid = threadIdx.x;  // 128
    float v[3];
    float ss = 0.f;
#pragma unroll
    for (int i = 0; i < 3; ++i) {
        int k = tid + i * 128;
        float t = (k < ED) ? src[k] : 0.f;
        v[i] = t;
        ss += t * t;
    }
    for (int off = 32; off > 0; off >>= 1) ss += __shfl_xor(ss, off, 64);
    __shared__ float red[2];
    if ((tid & 63) == 0) red[tid >> 6] = ss;
    __syncthreads();
    float nrm = sqrtf(red[0] + red[1]);
    float scale = fminf(1.0f, 5.0f / (nrm + 1e-7f));
#pragma unroll
    for (int i = 0; i < 3; ++i) {
        int k = tid + i * 128;
        if (k < ED) dst[k] = v[i] * scale;
    }
}

// ---------------------------------------------------------------------------
// K_prep_dir: Wt[300][1536] = Wih_dir^T, bc[1536] = bih_dir  (coalesced reads)
// ---------------------------------------------------------------------------
__global__ void k_prep_dir(const float* __restrict__ Wih, const float* __restrict__ bih,
                           float* __restrict__ Wt, float* __restrict__ bc) {
    int idx = blockIdx.x * blockDim.x + threadIdx.x;
    int stride = gridDim.x * blockDim.x;
    for (int i = idx; i < ED * G3; i += stride) {
        int n = i / ED, k = i - n * ED;
        Wt[(size_t)k * G3 + n] = Wih[i];
    }
    for (int i = idx; i < G3; i += stride) bc[i] = bih[i];
}

// K_prep_w1: W1at[1024][256] = transpose of W1[:, :1024]  (coalesced reads)
__global__ void k_prep_w1(const float* __restrict__ W1, float* __restrict__ W1at) {
    int idx = blockIdx.x * blockDim.x + threadIdx.x;
    int stride = gridDim.x * blockDim.x;
    for (int i = idx; i < 1024 * ATT_; i += stride) {
        int n = i >> 10, k = i & 1023;
        W1at[(size_t)k * ATT_ + n] = W1[(size_t)n * 2048 + k];
    }
}

// ---------------------------------------------------------------------------
// fp32 GEMM, 128x128 tile, 256 threads, 8x8 per thread, float4 LDS reads.
// ---------------------------------------------------------------------------
#define BSKEW(n) ((n) + (((n) >> 5) << 2))

template <int KT, int EPI>
__global__ void __launch_bounds__(256) k_gemm128(
    const float* __restrict__ A, int lda, long strideA,
    const float* __restrict__ Bm, int ldb, long strideB,
    float* __restrict__ C, int ldc, long strideC,
    int M, int N, int K,
    const float* __restrict__ bias, const float* __restrict__ bias2) {
    __shared__ float As[KT * 132];
    __shared__ float Bs[KT * 144];
    const int tid = threadIdx.x;
    const int tx = tid & 15, ty = tid >> 4;
    const int mbase = blockIdx.y * 128, nbase = blockIdx.x * 128;
    const float* Ab = A + (long)blockIdx.z * strideA;
    const float* Bb = Bm + (long)blockIdx.z * strideB;
    float* Cb = C + (long)blockIdx.z * strideC;
    float acc[8][8] = {};
    const int bgrp = tx * 8 + ((tx >> 2) << 2);
    for (int k0 = 0; k0 < K; k0 += KT) {
        for (int i = tid; i < 128 * KT; i += 256) {
            int r = i / KT, c = i % KT;
            As[c * 132 + r] = Ab[(size_t)(mbase + r) * lda + k0 + c];
        }
        for (int i = tid; i < KT * 128; i += 256) {
            int kk = i >> 7, n = i & 127;
            Bs[kk * 144 + BSKEW(n)] = Bb[(size_t)(k0 + kk) * ldb + nbase + n];
        }
        __syncthreads();
#pragma unroll
        for (int kk = 0; kk < KT; ++kk) {
            const float4* pa = (const float4*)&As[kk * 132 + ty * 8];
            float4 a0 = pa[0], a1 = pa[1];
            const float4* pb = (const float4*)&Bs[kk * 144 + bgrp];
            float4 b0 = pb[0], b1 = pb[1];
            float av[8] = {a0.x, a0.y, a0.z, a0.w, a1.x, a1.y, a1.z, a1.w};
            float bv[8] = {b0.x, b0.y, b0.z, b0.w, b1.x, b1.y, b1.z, b1.w};
#pragma unroll
            for (int i = 0; i < 8; ++i)
#pragma unroll
                for (int j = 0; j < 8; ++j) acc[i][j] += av[i] * bv[j];
        }
        __syncthreads();
    }
#pragma unroll
    for (int i = 0; i < 8; ++i) {
        int row = mbase + ty * 8 + i;
        float vout[8];
#pragma unroll
        for (int j = 0; j < 8; ++j) {
            int col = nbase + tx * 8 + j;
            float v = acc[i][j];
            if (EPI == 1) v += bias[col];
            if (EPI == 2) v = tanhf(v + bias2[(size_t)(row >> 8) * ATT_ + col]);
            vout[j] = v;
        }
        float4* cp = (float4*)&Cb[(size_t)row * ldc + nbase + tx * 8];
        cp[0] = make_float4(vout[0], vout[1], vout[2], vout[3]);
        cp[1] = make_float4(vout[4], vout[5], vout[6], vout[7]);
    }
}

// ---------------------------------------------------------------------------
// GRU helpers
// ---------------------------------------------------------------------------
__device__ __forceinline__ float sigmoidf_(float v) { return 1.f / (1.f + expf(-v)); }

// ---------------------------------------------------------------------------
// Cooperative persistent GRU, one direction.  256 blocks x 512 threads.
// Hierarchical grid barrier: 8 group counters (32 blocks each, 128B-padded
// lines) -> 1 root (8 masters) -> 8 per-group 'go' lines.  Cuts same-line
// cross-XCD RMW contention from 256 to <=32 per line.
// bar layout (uints): [0..255] grp (8x32), [256..287] root, [288..543] go
// ---------------------------------------------------------------------------
__global__ void __launch_bounds__(512)
k_gru_coop(const float* __restrict__ xw,   // [B,S,1536] this dir
           const float* __restrict__ Whh, const float* __restrict__ bhh,
           float* __restrict__ h_all, int dir, unsigned* __restrict__ bar) {
    const int bu = blockIdx.x;          // 0..255
    const int tid = threadIdx.x;        // 0..511
    const int b  = tid >> 3;            // 0..63
    const int ul = (tid >> 2) & 1;      // unit within block
    const int kh = tid & 3;             // K quarter
    const int ug = bu * 2 + ul;         // global unit
    unsigned* gc   = bar + ((bu >> 5) << 5);
    unsigned* root = bar + 256;
    unsigned* go   = bar + 288 + ((bu >> 5) << 5);
    const bool master = (bu & 31) == 0;
    __shared__ float Ws[3][2][4][132];  // ~12.7 KB, bank-quad padded
    __shared__ float bsh[3][2];
    for (int t = tid; t < 3072; t += 512) {
        int g = t >> 10, r = t & 1023, u = r >> 9, k = r & 511;
        Ws[g][u][k >> 7][k & 127] = Whh[(size_t)(g * 512 + bu * 2 + u) * 512 + k];
    }
    if (tid < 6) bsh[tid >> 1][tid & 1] = bhh[(tid >> 1) * 512 + bu * 2 + (tid & 1)];
    __syncthreads();
    float hcur = 0.f;
    for (int i = 0; i < 256; ++i) {
        const int pos = dir ? (255 - i) : i;
        // prefetch this step's input-projection row (independent of h(t-1));
        // the HBM latency hides under the barrier spin.
        const float* __restrict__ xrow = xw + ((size_t)b * 256 + pos) * 1536;
        float xr = xrow[ug], xz = xrow[512 + ug], xn = xrow[1024 + ug];
        float hr = 0.f, hz = 0.f, hn = 0.f;
        float hold = 0.f;
        if (i > 0) {
            // ---- hierarchical grid barrier ----
            __syncthreads();   // drains vmcnt: this block's h store is in L2
            if (tid == 0) {
                __threadfence();                       // release
                __hip_atomic_fetch_add(gc, 1u, __ATOMIC_RELEASE,
                                       __HIP_MEMORY_SCOPE_AGENT);
                if (master) {
                    while (__hip_atomic_load(gc, __ATOMIC_ACQUIRE,
                                             __HIP_MEMORY_SCOPE_AGENT)
                           < 32u * (unsigned)i)
                        __builtin_amdgcn_s_sleep(1);
                    __hip_atomic_fetch_add(root, 1u, __ATOMIC_RELEASE,
                                           __HIP_MEMORY_SCOPE_AGENT);
                    while (__hip_atomic_load(root, __ATOMIC_ACQUIRE,
                                             __HIP_MEMORY_SCOPE_AGENT)
                           < 8u * (unsigned)i)
                        __builtin_amdgcn_s_sleep(1);
                    __hip_atomic_store(go, (unsigned)i, __ATOMIC_RELEASE,
                                       __HIP_MEMORY_SCOPE_AGENT);
                } else {
                    while (__hip_atomic_load(go, __ATOMIC_ACQUIRE,
                                             __HIP_MEMORY_SCOPE_AGENT)
                           < (unsigned)i)
                        __builtin_amdgcn_s_sleep(1);
                }
                __threadfence();                       // acquire
            }
            __syncthreads();
            const int ppos = dir ? (pos + 1) : (pos - 1);
            const float* hrow = h_all + ((size_t)b * 256 + ppos) * 1024 + dir * 512;
            hold = hrow[ug];
            const float4* __restrict__ hp = (const float4*)(hrow + kh * 128);
            const float4* __restrict__ w0 = (const float4*)(&Ws[0][ul][kh][0]);
            const float4* __restrict__ w1 = (const float4*)(&Ws[1][ul][kh][0]);
            const float4* __restrict__ w2 = (const float4*)(&Ws[2][ul][kh][0]);
#pragma unroll 8
            for (int k4 = 0; k4 < 32; ++k4) {
                float4 h4 = hp[k4];
                float4 a = w0[k4]; hr += h4.x * a.x + h4.y * a.y + h4.z * a.z + h4.w * a.w;
                float4 c = w1[k4]; hz += h4.x * c.x + h4.y * c.y + h4.z * c.z + h4.w * c.w;
                float4 d = w2[k4]; hn += h4.x * d.x + h4.y * d.y + h4.z * d.z + h4.w * d.w;
            }
            hr += __shfl_xor(hr, 1, 64); hr += __shfl_xor(hr, 2, 64);
            hz += __shfl_xor(hz, 1, 64); hz += __shfl_xor(hz, 2, 64);
            hn += __shfl_xor(hn, 1, 64); hn += __shfl_xor(hn, 2, 64);
        }
        float r = sigmoidf_(xr + bsh[0][ul] + hr);
        float z = sigmoidf_(xz + bsh[1][ul] + hz);
        float n = tanhf(xn + r * (bsh[2][ul] + hn));
        hcur = (1.f - z) * n + z * hold;
        if (kh == 0)
            h_all[((size_t)b * 256 + pos) * 1024 + dir * 512 + ug] = hcur;
    }
}

// Fallback: one step per launch (proven in round 2)
__global__ void __launch_bounds__(256)
k_gru_step2(const float* __restrict__ xw,
            const float* __restrict__ Whh, const float* __restrict__ bhh,
            float* __restrict__ h_all, int i, int dir) {
    const int bu = blockIdx.x;
    const int tid = threadIdx.x;
    const int b  = tid >> 2;
    const int t2 = tid & 3;
    const int ul = t2 >> 1;
    const int kh = t2 & 1;
    const int ug = bu * 2 + ul;
    __shared__ float Ws[3][2][512];
    __shared__ float bsh[3][2];
    for (int t = tid; t < 3072; t += 256) {
        int g = t >> 10, u = (t >> 9) & 1, k = t & 511;
        Ws[g][u][k] = Whh[(size_t)(g * 512 + bu * 2 + u) * 512 + k];
    }
    if (tid < 6) bsh[tid >> 1][tid & 1] = bhh[(tid >> 1) * 512 + bu * 2 + (tid & 1)];
    __syncthreads();
    const int pos = dir ? (255 - i) : i;
    float hr = 0.f, hz = 0.f, hn = 0.f;
    float hold = 0.f;
    if (i > 0) {
        const int ppos = dir ? (pos + 1) : (pos - 1);
        const float* hrow = h_all + ((size_t)b * 256 + ppos) * 1024 + dir * 512;
        hold = hrow[ug];
        const float4* __restrict__ hp = (const float4*)(hrow + kh * 256);
        const float4* __restrict__ w0 = (const float4*)(&Ws[0][ul][kh * 256]);
        const float4* __restrict__ w1 = (const float4*)(&Ws[1][ul][kh * 256]);
        const float4* __restrict__ w2 = (const float4*)(&Ws[2][ul][kh * 256]);
#pragma unroll 8
        for (int k4 = 0; k4 < 64; ++k4) {
            float4 h4 = hp[k4];
            float4 a = w0[k4]; hr += h4.x * a.x + h4.y * a.y + h4.z * a.z + h4.w * a.w;
            float4 c = w1[k4]; hz += h4.x * c.x + h4.y * c.y + h4.z * c.z + h4.w * c.w;
            float4 d = w2[k4]; hn += h4.x * d.x + h4.y * d.y + h4.z * d.z + h4.w * d.w;
        }
    }
    hr += __shfl_xor(hr, 1, 64);
    hz += __shfl_xor(hz, 1, 64);
    hn += __shfl_xor(hn, 1, 64);
    const float* __restrict__ xrow = xw + ((size_t)b * 256 + pos) * 1536;
    float xr = xrow[ug], xz = xrow[512 + ug], xn = xrow[1024 + ug];
    float r = sigmoidf_(xr + bsh[0][ul] + hr);
    float z = sigmoidf_(xz + bsh[1][ul] + hz);
    float n = tanhf(xn + r * (bsh[2][ul] + hn));
    float hcur = (1.f - z) * n + z * hold;
    if (kh == 0)
        h_all[((size_t)b * 256 + pos) * 1024 + dir * 512 + ug] = hcur;
}

// ---------------------------------------------------------------------------
// K4: masked mean over target span -> target[b, 1024]
// ---------------------------------------------------------------------------
__global__ void k_target(const float* __restrict__ h_all, const int* __restrict__ ts,
                         const int* __restrict__ te, float* __restrict__ target) {
    int b = blockIdx.x;
    int tid = threadIdx.x;  // 256
    int s0 = ts[b], s1 = te[b];
    float inv = 1.f / (float)(s1 - s0 + 1);
    for (int d = tid; d < 1024; d += 256) {
        float acc = 0.f;
        for (int s = s0; s <= s1; ++s) acc += h_all[((size_t)b * 256 + s) * 1024 + d];
        target[(size_t)b * 1024 + d] = acc * inv;
    }
}

// ---------------------------------------------------------------------------
// K4b: tmp2[b,a] = b1[a] + target[b,:] . W1[a, 1024:2048]
// ---------------------------------------------------------------------------
__global__ void k_tmp2(const float* __restrict__ target, const float* __restrict__ W1,
                       const float* __restrict__ b1, float* __restrict__ tmp2) {
    int b = blockIdx.x;
    int a = threadIdx.x;  // 256
    __shared__ float tg[1024];
    for (int d = a; d < 1024; d += 256) tg[d] = target[(size_t)b * 1024 + d];
    __syncthreads();
    const float4* wrow = (const float4*)(W1 + (size_t)a * 2048 + 1024);
    const float4* tg4 = (const float4*)tg;
    float acc = b1[a];
    for (int k = 0; k < 256; ++k) {
        float4 w = wrow[k], t = tg4[k];
        acc += w.x * t.x + w.y * t.y + w.z * t.z + w.w * t.w;
    }
    tmp2[(size_t)b * ATT_ + a] = acc;
}

// ---------------------------------------------------------------------------
// transpose o[b][s][a] -> ot[b][a][s]
// ---------------------------------------------------------------------------
__global__ void k_transpose_o(const float* __restrict__ o, float* __restrict__ ot) {
    int b = blockIdx.z;
    __shared__ float t[32][33];
    int a0 = blockIdx.x * 32, s0 = blockIdx.y * 32;
    int tx = threadIdx.x & 31, ty = threadIdx.x >> 5;  // 32x8
    for (int i = ty; i < 32; i += 8)
        t[i][tx] = o[((size_t)b * 256 + s0 + i) * 256 + a0 + tx];
    __syncthreads();
    for (int i = ty; i < 32; i += 8)
        ot[((size_t)b * 256 + a0 + i) * 256 + s0 + tx] = t[tx][i];
}

// ---------------------------------------------------------------------------
// softmax over last axis, in place.  one block per (b,k) row of 256.
// ---------------------------------------------------------------------------
__global__ void k_softmax(float* __restrict__ beta) {
    int row = blockIdx.x;
    float* p = beta + (size_t)row * 256;
    int tid = threadIdx.x;  // 256
    float v = p[tid];
    float m = v;
    for (int off = 32; off > 0; off >>= 1) m = fmaxf(m, __shfl_xor(m, off, 64));
    __shared__ float red[4];
    if ((tid & 63) == 0) red[tid >> 6] = m;
    __syncthreads();
    m = fmaxf(fmaxf(red[0], red[1]), fmaxf(red[2], red[3]));
    float e = expf(v - m);
    float ssum = e;
    for (int off = 32; off > 0; off >>= 1) ssum += __shfl_xor(ssum, off, 64);
    __shared__ float red2[4];
    if ((tid & 63) == 0) red2[tid >> 6] = ssum;
    __syncthreads();
    float tot = red2[0] + red2[1] + red2[2] + red2[3];
    p[tid] = e / tot;
}

// ---------------------------------------------------------------------------
// final: out[row, 0:3] = result[row,:] . W2[l,:] + b2[l]
// ---------------------------------------------------------------------------
__global__ void k_final(const float* __restrict__ result, const float* __restrict__ W2,
                        const float* __restrict__ b2, float* __restrict__ out) {
    int row = blockIdx.x;
    int tid = threadIdx.x;  // 256
    const float* r = result + (size_t)row * 1024;
    float a0 = 0.f, a1 = 0.f, a2 = 0.f;
    for (int h = tid; h < 1024; h += 256) {
        float rv = r[h];
        a0 += rv * W2[h];
        a1 += rv * W2[1024 + h];
        a2 += rv * W2[2048 + h];
    }
    for (int off = 32; off > 0; off >>= 1) {
        a0 += __shfl_xor(a0, off, 64);
        a1 += __shfl_xor(a1, off, 64);
        a2 += __shfl_xor(a2, off, 64);
    }
    __shared__ float red[4][3];
    if ((tid & 63) == 0) {
        red[tid >> 6][0] = a0; red[tid >> 6][1] = a1; red[tid >> 6][2] = a2;
    }
    __syncthreads();
    if (tid < 3) {
        float s = red[0][tid] + red[1][tid] + red[2][tid] + red[3][tid];
        out[(size_t)row * 3 + tid] = s + b2[tid];
    }
}

// ---------------------------------------------------------------------------
extern "C" void kernel_launch(void* const* d_in, const int* in_sizes, int n_in,
                              void* d_out, int out_size, void* d_ws, size_t ws_size,
                              hipStream_t stream) {
    const int*   x      = (const int*)d_in[0];
    const int*   tstart = (const int*)d_in[1];
    const int*   tend   = (const int*)d_in[2];
    const float* emb    = (const float*)d_in[3];
    const float* Wihf   = (const float*)d_in[4];
    const float* Whhf   = (const float*)d_in[5];
    const float* bihf   = (const float*)d_in[6];
    const float* bhhf   = (const float*)d_in[7];
    const float* Wihb   = (const float*)d_in[8];
    const float* Whhb   = (const float*)d_in[9];
    const float* bihb   = (const float*)d_in[10];
    const float* bhhb   = (const float*)d_in[11];
    const float* W1     = (const float*)d_in[12];
    const float* b1     = (const float*)d_in[13];
    const float* u      = (const float*)d_in[14];
    const float* W2     = (const float*)d_in[15];
    const float* b2     = (const float*)d_in[16];
    float* out = (float*)d_out;
    float* ws = (float*)d_ws;

    // workspace layout (floats).  total ~= 47,666,048 floats = 190.7 MB
    float* h_p    = ws;                       // 16,777,216
    float* e_p    = h_p + 16777216;           // 4,915,200  (dead after 2nd xw GEMM)
    float* xw_p   = e_p + 4915200;            // 25,165,824 (per-dir; dead after GRUs)
    float* Wt_p   = xw_p + 25165824;          // 460,800
    float* bc_p   = Wt_p + 460800;            // 1,536
    float* W1at_p = bc_p + 1536;              // 262,144
    float* tg_p   = W1at_p + 262144;          // 65,536
    float* t2_p   = tg_p + 65536;             // 16,384
    unsigned* ctr_p = (unsigned*)(t2_p + 16384);  // 2 dirs x 544 uints (barriers)
    // aliases into dead regions (after both GRU passes):
    float* o_p    = e_p;                      // 4,194,304 <= 4,915,200
    float* res_p  = xw_p;                     // 16,777,216
    float* ot_p   = xw_p + 16777216;          // 4,194,304
    float* beta_p = xw_p + 20971520;          // 4,194,304

    if (ws_size < (size_t)47666048 * 4) return;  // refuse to overflow scratch

    // 0. zero barrier counters (every call / graph replay)
    hipMemsetAsync(ctr_p, 0, 2 * 544 * sizeof(unsigned), stream);
    // 1. embedding + renorm
    k_embed<<<BS_, 128, 0, stream>>>(x, emb, e_p);
    // 2. W1 transpose (once)
    k_prep_w1<<<256, 256, 0, stream>>>(W1, W1at_p);
    // 3. per-direction: input proj GEMM, then persistent cooperative GRU
    for (int dir = 0; dir < 2; ++dir) {
        const float* Wih = dir ? Wihb : Wihf;
        const float* bih = dir ? bihb : bihf;
        const float* Whh = dir ? Whhb : Whhf;
        const float* bhh = dir ? bhhb : bhhf;
        k_prep_dir<<<512, 256, 0, stream>>>(Wih, bih, Wt_p, bc_p);
        k_gemm128<20, 1><<<dim3(12, 128, 1), 256, 0, stream>>>(
            e_p, ED, 0, Wt_p, G3, 0, xw_p, G3, 0, BS_, G3, ED, bc_p, nullptr);
        {
            const float* a0 = xw_p; const float* a1 = Whh; const float* a2 = bhh;
            float* a3 = h_p; int a4 = dir; unsigned* a5 = ctr_p + dir * 544;
            void* args[] = {&a0, &a1, &a2, &a3, &a4, &a5};
            hipError_t ce = hipLaunchCooperativeKernel((void*)k_gru_coop,
                                                       dim3(256, 1, 1), dim3(512, 1, 1),
                                                       args, 0, stream);
            if (ce != hipSuccess) {
                for (int i = 0; i < 256; ++i)
                    k_gru_step2<<<256, 256, 0, stream>>>(xw_p, Whh, bhh, h_p, i, dir);
            }
        }
    }
    // 4. target span mean
    k_target<<<BB, 256, 0, stream>>>(h_p, tstart, tend, tg_p);
    // 5. tmp2[b,a] = b1 + target . W1[:,1024:]
    k_tmp2<<<BB, 256, 0, stream>>>(tg_p, W1, b1, t2_p);
    // 6. o = tanh(h @ W1a^T + tmp2)   [16384, 256]
    k_gemm128<16, 2><<<dim3(2, 128, 1), 256, 0, stream>>>(
        h_p, 1024, 0, W1at_p, ATT_, 0, o_p, ATT_, 0, BS_, ATT_, 1024, nullptr, t2_p);
    // 7. transpose o -> ot[b][a][s]
    k_transpose_o<<<dim3(8, 8, BB), 256, 0, stream>>>(o_p, ot_p);
    // 8. beta[b][k][s] = u @ ot[b]
    k_gemm128<16, 0><<<dim3(2, 2, BB), 256, 0, stream>>>(
        u, ATT_, 0, ot_p, ATT_, 65536, beta_p, ATT_, 65536, ATT_, ATT_, ATT_, nullptr, nullptr);
    // 9. softmax over s (in place)
    k_softmax<<<BS_, 256, 0, stream>>>(beta_p);
    // 10. result[b][k][h] = alfa[b] @ h[b]
    k_gemm128<16, 0><<<dim3(8, 2, BB), 256, 0, stream>>>(
        beta_p, ATT_, 65536, h_p, 1024, 262144, res_p, 1024, 262144,
        ATT_, 1024, ATT_, nullptr, nullptr);
    // 11. final linear
    k_final<<<BS_, 256, 0, stream>>>(res_p, W2, b2, out);
}

// Round 6
// 12553.029 us; speedup vs baseline: 1.8417x; 1.8417x over previous
//
#include <hip/hip_runtime.h>
#include <math.h>

// Problem constants
#define BB   64
#define SS   256
#define ED   300
#define HH   512
#define G3   1536   // 3*H (one direction)
#define ATT_ 256
#define BS_  16384  // BB*SS

// ---------------------------------------------------------------------------
// K1: embedding gather + max-norm renorm.  one block per (b,s) row, 128 thr
// ---------------------------------------------------------------------------
__global__ void k_embed(const int* __restrict__ x, const float* __restrict__ emb,
                        float* __restrict__ e) {
    int row = blockIdx.x;
    int tok = x[row];
    const float* src = emb + (size_t)tok * ED;
    float* dst = e + (size_t)row * ED;
    int tid = threadIdx.x;  // 128
    float v[3];
    float ss = 0.f;
#pragma unroll
    for (int i = 0; i < 3; ++i) {
        int k = tid + i * 128;
        float t = (k < ED) ? src[k] : 0.f;
        v[i] = t;
        ss += t * t;
    }
    for (int off = 32; off > 0; off >>= 1) ss += __shfl_xor(ss, off, 64);
    __shared__ float red[2];
    if ((tid & 63) == 0) red[tid >> 6] = ss;
    __syncthreads();
    float nrm = sqrtf(red[0] + red[1]);
    float scale = fminf(1.0f, 5.0f / (nrm + 1e-7f));
#pragma unroll
    for (int i = 0; i < 3; ++i) {
        int k = tid + i * 128;
        if (k < ED) dst[k] = v[i] * scale;
    }
}

// ---------------------------------------------------------------------------
// K_prep_dir: Wt[300][1536] = Wih_dir^T, bc[1536] = bih_dir  (coalesced reads)
// ---------------------------------------------------------------------------
__global__ void k_prep_dir(const float* __restrict__ Wih, const float* __restrict__ bih,
                           float* __restrict__ Wt, float* __restrict__ bc) {
    int idx = blockIdx.x * blockDim.x + threadIdx.x;
    int stride = gridDim.x * blockDim.x;
    for (int i = idx; i < ED * G3; i += stride) {
        int n = i / ED, k = i - n * ED;
        Wt[(size_t)k * G3 + n] = Wih[i];
    }
    for (int i = idx; i < G3; i += stride) bc[i] = bih[i];
}

// K_prep_w1: W1at[1024][256] = transpose of W1[:, :1024]  (coalesced reads)
__global__ void k_prep_w1(const float* __restrict__ W1, float* __restrict__ W1at) {
    int idx = blockIdx.x * blockDim.x + threadIdx.x;
    int stride = gridDim.x * blockDim.x;
    for (int i = idx; i < 1024 * ATT_; i += stride) {
        int n = i >> 10, k = i & 1023;
        W1at[(size_t)k * ATT_ + n] = W1[(size_t)n * 2048 + k];
    }
}

// K_pack_whh: Wp[kq][row][4] = Whh[row][4*kq .. 4*kq+3]   (kq = k/4)
// Lane-dense layout for the GRU matvec: for fixed kq, consecutive rows are
// consecutive float4s -> a wave (lane = row) reads 1KB contiguous per load.
__global__ void k_pack_whh(const float* __restrict__ Whh, float* __restrict__ Wp) {
    int idx = blockIdx.x * blockDim.x + threadIdx.x;
    int stride = gridDim.x * blockDim.x;
    for (int i = idx; i < HH * G3; i += stride) {
        int r = i >> 9, k = i & 511;    // coalesced read of Whh
        Wp[((size_t)(k >> 2) * G3 + r) * 4 + (k & 3)] = Whh[i];
    }
}

// ---------------------------------------------------------------------------
// fp32 GEMM, 128x128 tile, 256 threads, 8x8 per thread, float4 LDS reads.
// ---------------------------------------------------------------------------
#define BSKEW(n) ((n) + (((n) >> 5) << 2))

template <int KT, int EPI>
__global__ void __launch_bounds__(256) k_gemm128(
    const float* __restrict__ A, int lda, long strideA,
    const float* __restrict__ Bm, int ldb, long strideB,
    float* __restrict__ C, int ldc, long strideC,
    int M, int N, int K,
    const float* __restrict__ bias, const float* __restrict__ bias2) {
    __shared__ float As[KT * 132];
    __shared__ float Bs[KT * 144];
    const int tid = threadIdx.x;
    const int tx = tid & 15, ty = tid >> 4;
    const int mbase = blockIdx.y * 128, nbase = blockIdx.x * 128;
    const float* Ab = A + (long)blockIdx.z * strideA;
    const float* Bb = Bm + (long)blockIdx.z * strideB;
    float* Cb = C + (long)blockIdx.z * strideC;
    float acc[8][8] = {};
    const int bgrp = tx * 8 + ((tx >> 2) << 2);
    for (int k0 = 0; k0 < K; k0 += KT) {
        for (int i = tid; i < 128 * KT; i += 256) {
            int r = i / KT, c = i % KT;
            As[c * 132 + r] = Ab[(size_t)(mbase + r) * lda + k0 + c];
        }
        for (int i = tid; i < KT * 128; i += 256) {
            int kk = i >> 7, n = i & 127;
            Bs[kk * 144 + BSKEW(n)] = Bb[(size_t)(k0 + kk) * ldb + nbase + n];
        }
        __syncthreads();
#pragma unroll
        for (int kk = 0; kk < KT; ++kk) {
            const float4* pa = (const float4*)&As[kk * 132 + ty * 8];
            float4 a0 = pa[0], a1 = pa[1];
            const float4* pb = (const float4*)&Bs[kk * 144 + bgrp];
            float4 b0 = pb[0], b1 = pb[1];
            float av[8] = {a0.x, a0.y, a0.z, a0.w, a1.x, a1.y, a1.z, a1.w};
            float bv[8] = {b0.x, b0.y, b0.z, b0.w, b1.x, b1.y, b1.z, b1.w};
#pragma unroll
            for (int i = 0; i < 8; ++i)
#pragma unroll
                for (int j = 0; j < 8; ++j) acc[i][j] += av[i] * bv[j];
        }
        __syncthreads();
    }
#pragma unroll
    for (int i = 0; i < 8; ++i) {
        int row = mbase + ty * 8 + i;
        float vout[8];
#pragma unroll
        for (int j = 0; j < 8; ++j) {
            int col = nbase + tx * 8 + j;
            float v = acc[i][j];
            if (EPI == 1) v += bias[col];
            if (EPI == 2) v = tanhf(v + bias2[(size_t)(row >> 8) * ATT_ + col]);
            vout[j] = v;
        }
        float4* cp = (float4*)&Cb[(size_t)row * ldc + nbase + tx * 8];
        cp[0] = make_float4(vout[0], vout[1], vout[2], vout[3]);
        cp[1] = make_float4(vout[4], vout[5], vout[6], vout[7]);
    }
}

// ---------------------------------------------------------------------------
// GRU helpers
// ---------------------------------------------------------------------------
__device__ __forceinline__ float sigmoidf_(float v) { return 1.f / (1.f + expf(-v)); }

// ---------------------------------------------------------------------------
// Block-private GRU: one block per batch element, ZERO cross-block sync.
// 64 blocks x 768 threads, one launch per direction.
// h(t) lives in LDS (hs[512]); weights streamed from L2 each step in the
// packed lane-dense layout (Wp).  Thread owns rows {tid, 768+tid}; per 4-k
// it reads 2 dense b128 weight quads + 1 broadcast b128 of h.
// Phase 2 (tid<512): per-unit gate update, write hs + h_all.
// ---------------------------------------------------------------------------
__global__ void __launch_bounds__(768)
k_gru_priv(const float* __restrict__ xw,   // [B,S,1536] this dir
           const float* __restrict__ Wp,   // packed Whh
           const float* __restrict__ bhh,
           float* __restrict__ h_all, int dir) {
    const int b = blockIdx.x;
    const int tid = threadIdx.x;
    __shared__ __align__(16) float hs[512];
    __shared__ float gact[1536];
    for (int t = tid; t < 512; t += 768) hs[t] = 0.f;
    float b0 = 0.f, b1 = 0.f, b2 = 0.f;
    if (tid < 512) { b0 = bhh[tid]; b1 = bhh[512 + tid]; b2 = bhh[1024 + tid]; }
    __syncthreads();
    const float4* __restrict__ hs4 = (const float4*)hs;
    const float4* __restrict__ wp = (const float4*)Wp + tid;
    for (int i = 0; i < 256; ++i) {
        const int pos = dir ? (255 - i) : i;
        // prefetch phase-2 inputs (independent of h) early
        float xr = 0.f, xz = 0.f, xn = 0.f;
        if (tid < 512) {
            const float* __restrict__ xrow = xw + ((size_t)b * 256 + pos) * 1536;
            xr = xrow[tid]; xz = xrow[512 + tid]; xn = xrow[1024 + tid];
        }
        if (i > 0) {
            float acc0 = 0.f, acc1 = 0.f;
#pragma unroll 4
            for (int kq = 0; kq < 128; ++kq) {
                float4 h4 = hs4[kq];
                float4 w0 = wp[(size_t)kq * G3];
                float4 w1 = wp[(size_t)kq * G3 + 768];
                acc0 += h4.x * w0.x + h4.y * w0.y + h4.z * w0.z + h4.w * w0.w;
                acc1 += h4.x * w1.x + h4.y * w1.y + h4.z * w1.z + h4.w * w1.w;
            }
            gact[tid] = acc0;
            gact[768 + tid] = acc1;
        }
        __syncthreads();
        if (tid < 512) {
            float hr = (i > 0) ? gact[tid] : 0.f;
            float hz = (i > 0) ? gact[512 + tid] : 0.f;
            float hn = (i > 0) ? gact[1024 + tid] : 0.f;
            float r = sigmoidf_(xr + b0 + hr);
            float z = sigmoidf_(xz + b1 + hz);
            float n = tanhf(xn + r * (b2 + hn));
            float h = (1.f - z) * n + z * hs[tid];
            hs[tid] = h;
            h_all[((size_t)b * 256 + pos) * 1024 + dir * 512 + tid] = h;
        }
        __syncthreads();
    }
}

// ---------------------------------------------------------------------------
// K4: masked mean over target span -> target[b, 1024]
// ---------------------------------------------------------------------------
__global__ void k_target(const float* __restrict__ h_all, const int* __restrict__ ts,
                         const int* __restrict__ te, float* __restrict__ target) {
    int b = blockIdx.x;
    int tid = threadIdx.x;  // 256
    int s0 = ts[b], s1 = te[b];
    float inv = 1.f / (float)(s1 - s0 + 1);
    for (int d = tid; d < 1024; d += 256) {
        float acc = 0.f;
        for (int s = s0; s <= s1; ++s) acc += h_all[((size_t)b * 256 + s) * 1024 + d];
        target[(size_t)b * 1024 + d] = acc * inv;
    }
}

// ---------------------------------------------------------------------------
// K4b: tmp2[b,a] = b1[a] + target[b,:] . W1[a, 1024:2048]
// ---------------------------------------------------------------------------
__global__ void k_tmp2(const float* __restrict__ target, const float* __restrict__ W1,
                       const float* __restrict__ b1, float* __restrict__ tmp2) {
    int b = blockIdx.x;
    int a = threadIdx.x;  // 256
    __shared__ float tg[1024];
    for (int d = a; d < 1024; d += 256) tg[d] = target[(size_t)b * 1024 + d];
    __syncthreads();
    const float4* wrow = (const float4*)(W1 + (size_t)a * 2048 + 1024);
    const float4* tg4 = (const float4*)tg;
    float acc = b1[a];
    for (int k = 0; k < 256; ++k) {
        float4 w = wrow[k], t = tg4[k];
        acc += w.x * t.x + w.y * t.y + w.z * t.z + w.w * t.w;
    }
    tmp2[(size_t)b * ATT_ + a] = acc;
}

// ---------------------------------------------------------------------------
// transpose o[b][s][a] -> ot[b][a][s]
// ---------------------------------------------------------------------------
__global__ void k_transpose_o(const float* __restrict__ o, float* __restrict__ ot) {
    int b = blockIdx.z;
    __shared__ float t[32][33];
    int a0 = blockIdx.x * 32, s0 = blockIdx.y * 32;
    int tx = threadIdx.x & 31, ty = threadIdx.x >> 5;  // 32x8
    for (int i = ty; i < 32; i += 8)
        t[i][tx] = o[((size_t)b * 256 + s0 + i) * 256 + a0 + tx];
    __syncthreads();
    for (int i = ty; i < 32; i += 8)
        ot[((size_t)b * 256 + a0 + i) * 256 + s0 + tx] = t[tx][i];
}

// ---------------------------------------------------------------------------
// softmax over last axis, in place.  one block per (b,k) row of 256.
// ---------------------------------------------------------------------------
__global__ void k_softmax(float* __restrict__ beta) {
    int row = blockIdx.x;
    float* p = beta + (size_t)row * 256;
    int tid = threadIdx.x;  // 256
    float v = p[tid];
    float m = v;
    for (int off = 32; off > 0; off >>= 1) m = fmaxf(m, __shfl_xor(m, off, 64));
    __shared__ float red[4];
    if ((tid & 63) == 0) red[tid >> 6] = m;
    __syncthreads();
    m = fmaxf(fmaxf(red[0], red[1]), fmaxf(red[2], red[3]));
    float e = expf(v - m);
    float ssum = e;
    for (int off = 32; off > 0; off >>= 1) ssum += __shfl_xor(ssum, off, 64);
    __shared__ float red2[4];
    if ((tid & 63) == 0) red2[tid >> 6] = ssum;
    __syncthreads();
    float tot = red2[0] + red2[1] + red2[2] + red2[3];
    p[tid] = e / tot;
}

// ---------------------------------------------------------------------------
// final: out[row, 0:3] = result[row,:] . W2[l,:] + b2[l]
// ---------------------------------------------------------------------------
__global__ void k_final(const float* __restrict__ result, const float* __restrict__ W2,
                        const float* __restrict__ b2, float* __restrict__ out) {
    int row = blockIdx.x;
    int tid = threadIdx.x;  // 256
    const float* r = result + (size_t)row * 1024;
    float a0 = 0.f, a1 = 0.f, a2 = 0.f;
    for (int h = tid; h < 1024; h += 256) {
        float rv = r[h];
        a0 += rv * W2[h];
        a1 += rv * W2[1024 + h];
        a2 += rv * W2[2048 + h];
    }
    for (int off = 32; off > 0; off >>= 1) {
        a0 += __shfl_xor(a0, off, 64);
        a1 += __shfl_xor(a1, off, 64);
        a2 += __shfl_xor(a2, off, 64);
    }
    __shared__ float red[4][3];
    if ((tid & 63) == 0) {
        red[tid >> 6][0] = a0; red[tid >> 6][1] = a1; red[tid >> 6][2] = a2;
    }
    __syncthreads();
    if (tid < 3) {
        float s = red[0][tid] + red[1][tid] + red[2][tid] + red[3][tid];
        out[(size_t)row * 3 + tid] = s + b2[tid];
    }
}

// ---------------------------------------------------------------------------
extern "C" void kernel_launch(void* const* d_in, const int* in_sizes, int n_in,
                              void* d_out, int out_size, void* d_ws, size_t ws_size,
                              hipStream_t stream) {
    const int*   x      = (const int*)d_in[0];
    const int*   tstart = (const int*)d_in[1];
    const int*   tend   = (const int*)d_in[2];
    const float* emb    = (const float*)d_in[3];
    const float* Wihf   = (const float*)d_in[4];
    const float* Whhf   = (const float*)d_in[5];
    const float* bihf   = (const float*)d_in[6];
    const float* bhhf   = (const float*)d_in[7];
    const float* Wihb   = (const float*)d_in[8];
    const float* Whhb   = (const float*)d_in[9];
    const float* bihb   = (const float*)d_in[10];
    const float* bhhb   = (const float*)d_in[11];
    const float* W1     = (const float*)d_in[12];
    const float* b1     = (const float*)d_in[13];
    const float* u      = (const float*)d_in[14];
    const float* W2     = (const float*)d_in[15];
    const float* b2     = (const float*)d_in[16];
    float* out = (float*)d_out;
    float* ws = (float*)d_ws;

    // workspace layout (floats).  total = 48,452,160 floats = 193.8 MB
    float* h_p    = ws;                       // 16,777,216
    float* e_p    = h_p + 16777216;           // 4,915,200  (dead after 2nd xw GEMM)
    float* xw_p   = e_p + 4915200;            // 25,165,824 (per-dir; dead after GRUs)
    float* Wt_p   = xw_p + 25165824;          // 460,800
    float* bc_p   = Wt_p + 460800;            // 1,536
    float* W1at_p = bc_p + 1536;              // 262,144
    float* tg_p   = W1at_p + 262144;          // 65,536
    float* t2_p   = tg_p + 65536;             // 16,384
    float* pad_p  = t2_p + 16384;             // 1,088 (legacy pad)
    float* Wp_p   = pad_p + 1088;             // 786,432 (packed Whh, per dir)
    // aliases into dead regions (after both GRU passes):
    float* o_p    = e_p;                      // 4,194,304 <= 4,915,200
    float* res_p  = xw_p;                     // 16,777,216
    float* ot_p   = xw_p + 16777216;          // 4,194,304
    float* beta_p = xw_p + 20971520;          // 4,194,304

    if (ws_size < (size_t)48452160 * 4) return;  // refuse to overflow scratch

    // 1. embedding + renorm
    k_embed<<<BS_, 128, 0, stream>>>(x, emb, e_p);
    // 2. W1 transpose (once)
    k_prep_w1<<<256, 256, 0, stream>>>(W1, W1at_p);
    // 3. per-direction: input proj GEMM, then block-private GRU (no grid sync)
    for (int dir = 0; dir < 2; ++dir) {
        const float* Wih = dir ? Wihb : Wihf;
        const float* bih = dir ? bihb : bihf;
        const float* Whh = dir ? Whhb : Whhf;
        const float* bhh = dir ? bhhb : bhhf;
        k_prep_dir<<<512, 256, 0, stream>>>(Wih, bih, Wt_p, bc_p);
        k_pack_whh<<<512, 256, 0, stream>>>(Whh, Wp_p);
        k_gemm128<20, 1><<<dim3(12, 128, 1), 256, 0, stream>>>(
            e_p, ED, 0, Wt_p, G3, 0, xw_p, G3, 0, BS_, G3, ED, bc_p, nullptr);
        k_gru_priv<<<64, 768, 0, stream>>>(xw_p, Wp_p, bhh, h_p, dir);
    }
    // 4. target span mean
    k_target<<<BB, 256, 0, stream>>>(h_p, tstart, tend, tg_p);
    // 5. tmp2[b,a] = b1 + target . W1[:,1024:]
    k_tmp2<<<BB, 256, 0, stream>>>(tg_p, W1, b1, t2_p);
    // 6. o = tanh(h @ W1a^T + tmp2)   [16384, 256]
    k_gemm128<16, 2><<<dim3(2, 128, 1), 256, 0, stream>>>(
        h_p, 1024, 0, W1at_p, ATT_, 0, o_p, ATT_, 0, BS_, ATT_, 1024, nullptr, t2_p);
    // 7. transpose o -> ot[b][a][s]
    k_transpose_o<<<dim3(8, 8, BB), 256, 0, stream>>>(o_p, ot_p);
    // 8. beta[b][k][s] = u @ ot[b]
    k_gemm128<16, 0><<<dim3(2, 2, BB), 256, 0, stream>>>(
        u, ATT_, 0, ot_p, ATT_, 65536, beta_p, ATT_, 65536, ATT_, ATT_, ATT_, nullptr, nullptr);
    // 9. softmax over s (in place)
    k_softmax<<<BS_, 256, 0, stream>>>(beta_p);
    // 10. result[b][k][h] = alfa[b] @ h[b]
    k_gemm128<16, 0><<<dim3(8, 2, BB), 256, 0, stream>>>(
        beta_p, ATT_, 65536, h_p, 1024, 262144, res_p, 1024, 262144,
        ATT_, 1024, ATT_, nullptr, nullptr);
    // 11. final linear
    k_final<<<BS_, 256, 0, stream>>>(res_p, W2, b2, out);
}

// Round 7
// 7390.465 us; speedup vs baseline: 3.1283x; 1.6985x over previous
//
#include <hip/hip_runtime.h>
#include <math.h>

// Problem constants
#define BB   64
#define SS   256
#define ED   300
#define HH   512
#define G3   1536   // 3*H (one direction)
#define ATT_ 256
#define BS_  16384  // BB*SS
#define CHK  64     // timesteps per chunk
#define NCHK 4

// ---------------------------------------------------------------------------
// K1: embedding gather + max-norm renorm.  one block per (b,s) row, 128 thr
// ---------------------------------------------------------------------------
__global__ void k_embed(const int* __restrict__ x, const float* __restrict__ emb,
                        float* __restrict__ e) {
    int row = blockIdx.x;
    int tok = x[row];
    const float* src = emb + (size_t)tok * ED;
    float* dst = e + (size_t)row * ED;
    int tid = threadIdx.x;  // 128
    float v[3];
    float ss = 0.f;
#pragma unroll
    for (int i = 0; i < 3; ++i) {
        int k = tid + i * 128;
        float t = (k < ED) ? src[k] : 0.f;
        v[i] = t;
        ss += t * t;
    }
    for (int off = 32; off > 0; off >>= 1) ss += __shfl_xor(ss, off, 64);
    __shared__ float red[2];
    if ((tid & 63) == 0) red[tid >> 6] = ss;
    __syncthreads();
    float nrm = sqrtf(red[0] + red[1]);
    float scale = fminf(1.0f, 5.0f / (nrm + 1e-7f));
#pragma unroll
    for (int i = 0; i < 3; ++i) {
        int k = tid + i * 128;
        if (k < ED) dst[k] = v[i] * scale;
    }
}

// ---------------------------------------------------------------------------
// K_prep_dir: Wt[300][1536] = Wih_dir^T, bc[1536] = bih_dir  (coalesced reads)
// ---------------------------------------------------------------------------
__global__ void k_prep_dir(const float* __restrict__ Wih, const float* __restrict__ bih,
                           float* __restrict__ Wt, float* __restrict__ bc) {
    int idx = blockIdx.x * blockDim.x + threadIdx.x;
    int stride = gridDim.x * blockDim.x;
    for (int i = idx; i < ED * G3; i += stride) {
        int n = i / ED, k = i - n * ED;
        Wt[(size_t)k * G3 + n] = Wih[i];
    }
    for (int i = idx; i < G3; i += stride) bc[i] = bih[i];
}

// K_prep_w1: W1at[1024][256] = transpose of W1[:, :1024]  (coalesced reads)
__global__ void k_prep_w1(const float* __restrict__ W1, float* __restrict__ W1at) {
    int idx = blockIdx.x * blockDim.x + threadIdx.x;
    int stride = gridDim.x * blockDim.x;
    for (int i = idx; i < 1024 * ATT_; i += stride) {
        int n = i >> 10, k = i & 1023;
        W1at[(size_t)k * ATT_ + n] = W1[(size_t)n * 2048 + k];
    }
}

// K_pack_whh: Wp[kq][row][4] = Whh[row][4*kq .. 4*kq+3]   (kq = k/4)
__global__ void k_pack_whh(const float* __restrict__ Whh, float* __restrict__ Wp) {
    int idx = blockIdx.x * blockDim.x + threadIdx.x;
    int stride = gridDim.x * blockDim.x;
    for (int i = idx; i < HH * G3; i += stride) {
        int r = i >> 9, k = i & 511;    // coalesced read of Whh
        Wp[((size_t)(k >> 2) * G3 + r) * 4 + (k & 3)] = Whh[i];
    }
}

// ---------------------------------------------------------------------------
// fp32 GEMM, 128x128 tile, 256 threads, 8x8 per thread, float4 LDS reads.
// spos >= 0: A-row r maps to source row (r/64)*256 + spos + (r%64)
//            (chunked time-window gather for the GRU input projection).
// EPI: 0 = none, 1 = +bias[n], 2 = tanh(acc + bias2[(row>>8)*256 + n])
// ---------------------------------------------------------------------------
#define BSKEW(n) ((n) + (((n) >> 5) << 2))

template <int KT, int EPI>
__global__ void __launch_bounds__(256) k_gemm128(
    const float* __restrict__ A, int lda, long strideA,
    const float* __restrict__ Bm, int ldb, long strideB,
    float* __restrict__ C, int ldc, long strideC,
    int M, int N, int K,
    const float* __restrict__ bias, const float* __restrict__ bias2,
    int spos) {
    __shared__ float As[KT * 132];
    __shared__ float Bs[KT * 144];
    const int tid = threadIdx.x;
    const int tx = tid & 15, ty = tid >> 4;
    const int mbase = blockIdx.y * 128, nbase = blockIdx.x * 128;
    const float* Ab = A + (long)blockIdx.z * strideA;
    const float* Bb = Bm + (long)blockIdx.z * strideB;
    float* Cb = C + (long)blockIdx.z * strideC;
    float acc[8][8] = {};
    const int bgrp = tx * 8 + ((tx >> 2) << 2);
    for (int k0 = 0; k0 < K; k0 += KT) {
        for (int i = tid; i < 128 * KT; i += 256) {
            int r = i / KT, c = i % KT;
            int row = mbase + r;
            int arow = (spos >= 0) ? ((row >> 6) * 256 + spos + (row & 63)) : row;
            As[c * 132 + r] = Ab[(size_t)arow * lda + k0 + c];
        }
        for (int i = tid; i < KT * 128; i += 256) {
            int kk = i >> 7, n = i & 127;
            Bs[kk * 144 + BSKEW(n)] = Bb[(size_t)(k0 + kk) * ldb + nbase + n];
        }
        __syncthreads();
#pragma unroll
        for (int kk = 0; kk < KT; ++kk) {
            const float4* pa = (const float4*)&As[kk * 132 + ty * 8];
            float4 a0 = pa[0], a1 = pa[1];
            const float4* pb = (const float4*)&Bs[kk * 144 + bgrp];
            float4 b0 = pb[0], b1 = pb[1];
            float av[8] = {a0.x, a0.y, a0.z, a0.w, a1.x, a1.y, a1.z, a1.w};
            float bv[8] = {b0.x, b0.y, b0.z, b0.w, b1.x, b1.y, b1.z, b1.w};
#pragma unroll
            for (int i = 0; i < 8; ++i)
#pragma unroll
                for (int j = 0; j < 8; ++j) acc[i][j] += av[i] * bv[j];
        }
        __syncthreads();
    }
#pragma unroll
    for (int i = 0; i < 8; ++i) {
        int row = mbase + ty * 8 + i;
        float vout[8];
#pragma unroll
        for (int j = 0; j < 8; ++j) {
            int col = nbase + tx * 8 + j;
            float v = acc[i][j];
            if (EPI == 1) v += bias[col];
            if (EPI == 2) v = tanhf(v + bias2[(size_t)(row >> 8) * ATT_ + col]);
            vout[j] = v;
        }
        float4* cp = (float4*)&Cb[(size_t)row * ldc + nbase + tx * 8];
        cp[0] = make_float4(vout[0], vout[1], vout[2], vout[3]);
        cp[1] = make_float4(vout[4], vout[5], vout[6], vout[7]);
    }
}

// ---------------------------------------------------------------------------
// GRU helpers
// ---------------------------------------------------------------------------
__device__ __forceinline__ float sigmoidf_(float v) { return 1.f / (1.f + expf(-v)); }

// ---------------------------------------------------------------------------
// Fused both-direction block-private GRU, chunked over time.
// 128 blocks = (dir, b); block maps dir by (bid&7)>>2 so each XCD (likely
// bid%8) serves one direction's 3MB weight set from its L2.
// Processes CHK steps of chunk c; h state carried in LDS within the chunk
// and through h_all across chunk launches (kernel boundary = global sync).
// xw chunk layout: [b][64][1536]; dir1 chunk rows are ascending pos.
// ---------------------------------------------------------------------------
__global__ void __launch_bounds__(768)
k_gru_priv2(const float* __restrict__ xw0, const float* __restrict__ xw1,
            const float* __restrict__ Wp,   // packed Whh, both dirs
            const float* __restrict__ bhhf, const float* __restrict__ bhhb,
            float* __restrict__ h_all, int c) {
    const int bid = blockIdx.x;
    const int xcd = bid & 7;
    const int dir = xcd >> 2;
    const int b = (bid >> 3) * 4 + (xcd & 3);
    const int tid = threadIdx.x;
    const float* __restrict__ xwc = dir ? xw1 : xw0;
    const float* __restrict__ bhh = dir ? bhhb : bhhf;
    __shared__ __align__(16) float hs[512];
    __shared__ float gact[1536];
    if (c == 0) {
        for (int t = tid; t < 512; t += 768) hs[t] = 0.f;
    } else {
        const int prevpos = dir ? (256 - CHK * c) : (CHK * c - 1);
        for (int t = tid; t < 512; t += 768)
            hs[t] = h_all[((size_t)b * 256 + prevpos) * 1024 + dir * 512 + t];
    }
    float b0 = 0.f, b1 = 0.f, b2 = 0.f;
    if (tid < 512) { b0 = bhh[tid]; b1 = bhh[512 + tid]; b2 = bhh[1024 + tid]; }
    __syncthreads();
    const float4* __restrict__ hs4 = (const float4*)hs;
    const float4* __restrict__ wp = (const float4*)(Wp + (size_t)dir * 786432) + tid;
    for (int j = 0; j < CHK; ++j) {
        const int gi = c * CHK + j;               // global step
        const int pos = dir ? (255 - gi) : gi;    // sequence position
        const int crow = b * CHK + (dir ? (CHK - 1 - j) : j);  // chunk row
        // prefetch phase-2 inputs (independent of h) early
        float xr = 0.f, xz = 0.f, xn = 0.f;
        if (tid < 512) {
            const float* __restrict__ xrow = xwc + (size_t)crow * 1536;
            xr = xrow[tid]; xz = xrow[512 + tid]; xn = xrow[1024 + tid];
        }
        if (gi > 0) {
            float acc0 = 0.f, acc1 = 0.f;
#pragma unroll 4
            for (int kq = 0; kq < 128; ++kq) {
                float4 h4 = hs4[kq];
                float4 w0 = wp[(size_t)kq * G3];
                float4 w1 = wp[(size_t)kq * G3 + 768];
                acc0 += h4.x * w0.x + h4.y * w0.y + h4.z * w0.z + h4.w * w0.w;
                acc1 += h4.x * w1.x + h4.y * w1.y + h4.z * w1.z + h4.w * w1.w;
            }
            gact[tid] = acc0;
            gact[768 + tid] = acc1;
        }
        __syncthreads();
        if (tid < 512) {
            float hr = (gi > 0) ? gact[tid] : 0.f;
            float hz = (gi > 0) ? gact[512 + tid] : 0.f;
            float hn = (gi > 0) ? gact[1024 + tid] : 0.f;
            float r = sigmoidf_(xr + b0 + hr);
            float z = sigmoidf_(xz + b1 + hz);
            float n = tanhf(xn + r * (b2 + hn));
            float h = (1.f - z) * n + z * hs[tid];
            hs[tid] = h;
            h_all[((size_t)b * 256 + pos) * 1024 + dir * 512 + tid] = h;
        }
        __syncthreads();
    }
}

// ---------------------------------------------------------------------------
// K4: masked mean over target span -> target[b, 1024]
// ---------------------------------------------------------------------------
__global__ void k_target(const float* __restrict__ h_all, const int* __restrict__ ts,
                         const int* __restrict__ te, float* __restrict__ target) {
    int b = blockIdx.x;
    int tid = threadIdx.x;  // 256
    int s0 = ts[b], s1 = te[b];
    float inv = 1.f / (float)(s1 - s0 + 1);
    for (int d = tid; d < 1024; d += 256) {
        float acc = 0.f;
        for (int s = s0; s <= s1; ++s) acc += h_all[((size_t)b * 256 + s) * 1024 + d];
        target[(size_t)b * 1024 + d] = acc * inv;
    }
}

// ---------------------------------------------------------------------------
// K4b: tmp2[b,a] = b1[a] + target[b,:] . W1[a, 1024:2048]
// ---------------------------------------------------------------------------
__global__ void k_tmp2(const float* __restrict__ target, const float* __restrict__ W1,
                       const float* __restrict__ b1, float* __restrict__ tmp2) {
    int b = blockIdx.x;
    int a = threadIdx.x;  // 256
    __shared__ float tg[1024];
    for (int d = a; d < 1024; d += 256) tg[d] = target[(size_t)b * 1024 + d];
    __syncthreads();
    const float4* wrow = (const float4*)(W1 + (size_t)a * 2048 + 1024);
    const float4* tg4 = (const float4*)tg;
    float acc = b1[a];
    for (int k = 0; k < 256; ++k) {
        float4 w = wrow[k], t = tg4[k];
        acc += w.x * t.x + w.y * t.y + w.z * t.z + w.w * t.w;
    }
    tmp2[(size_t)b * ATT_ + a] = acc;
}

// ---------------------------------------------------------------------------
// transpose o[b][s][a] -> ot[b][a][s]
// ---------------------------------------------------------------------------
__global__ void k_transpose_o(const float* __restrict__ o, float* __restrict__ ot) {
    int b = blockIdx.z;
    __shared__ float t[32][33];
    int a0 = blockIdx.x * 32, s0 = blockIdx.y * 32;
    int tx = threadIdx.x & 31, ty = threadIdx.x >> 5;  // 32x8
    for (int i = ty; i < 32; i += 8)
        t[i][tx] = o[((size_t)b * 256 + s0 + i) * 256 + a0 + tx];
    __syncthreads();
    for (int i = ty; i < 32; i += 8)
        ot[((size_t)b * 256 + a0 + i) * 256 + s0 + tx] = t[tx][i];
}

// ---------------------------------------------------------------------------
// softmax over last axis, in place.  one block per (b,k) row of 256.
// ---------------------------------------------------------------------------
__global__ void k_softmax(float* __restrict__ beta) {
    int row = blockIdx.x;
    float* p = beta + (size_t)row * 256;
    int tid = threadIdx.x;  // 256
    float v = p[tid];
    float m = v;
    for (int off = 32; off > 0; off >>= 1) m = fmaxf(m, __shfl_xor(m, off, 64));
    __shared__ float red[4];
    if ((tid & 63) == 0) red[tid >> 6] = m;
    __syncthreads();
    m = fmaxf(fmaxf(red[0], red[1]), fmaxf(red[2], red[3]));
    float e = expf(v - m);
    float ssum = e;
    for (int off = 32; off > 0; off >>= 1) ssum += __shfl_xor(ssum, off, 64);
    __shared__ float red2[4];
    if ((tid & 63) == 0) red2[tid >> 6] = ssum;
    __syncthreads();
    float tot = red2[0] + red2[1] + red2[2] + red2[3];
    p[tid] = e / tot;
}

// ---------------------------------------------------------------------------
// final: out[row, 0:3] = result[row,:] . W2[l,:] + b2[l]
// ---------------------------------------------------------------------------
__global__ void k_final(const float* __restrict__ result, const float* __restrict__ W2,
                        const float* __restrict__ b2, float* __restrict__ out) {
    int row = blockIdx.x;
    int tid = threadIdx.x;  // 256
    const float* r = result + (size_t)row * 1024;
    float a0 = 0.f, a1 = 0.f, a2 = 0.f;
    for (int h = tid; h < 1024; h += 256) {
        float rv = r[h];
        a0 += rv * W2[h];
        a1 += rv * W2[1024 + h];
        a2 += rv * W2[2048 + h];
    }
    for (int off = 32; off > 0; off >>= 1) {
        a0 += __shfl_xor(a0, off, 64);
        a1 += __shfl_xor(a1, off, 64);
        a2 += __shfl_xor(a2, off, 64);
    }
    __shared__ float red[4][3];
    if ((tid & 63) == 0) {
        red[tid >> 6][0] = a0; red[tid >> 6][1] = a1; red[tid >> 6][2] = a2;
    }
    __syncthreads();
    if (tid < 3) {
        float s = red[0][tid] + red[1][tid] + red[2][tid] + red[3][tid];
        out[(size_t)row * 3 + tid] = s + b2[tid];
    }
}

// ---------------------------------------------------------------------------
extern "C" void kernel_launch(void* const* d_in, const int* in_sizes, int n_in,
                              void* d_out, int out_size, void* d_ws, size_t ws_size,
                              hipStream_t stream) {
    const int*   x      = (const int*)d_in[0];
    const int*   tstart = (const int*)d_in[1];
    const int*   tend   = (const int*)d_in[2];
    const float* emb    = (const float*)d_in[3];
    const float* Wihf   = (const float*)d_in[4];
    const float* Whhf   = (const float*)d_in[5];
    const float* bihf   = (const float*)d_in[6];
    const float* bhhf   = (const float*)d_in[7];
    const float* Wihb   = (const float*)d_in[8];
    const float* Whhb   = (const float*)d_in[9];
    const float* bihb   = (const float*)d_in[10];
    const float* bhhb   = (const float*)d_in[11];
    const float* W1     = (const float*)d_in[12];
    const float* b1     = (const float*)d_in[13];
    const float* u      = (const float*)d_in[14];
    const float* W2     = (const float*)d_in[15];
    const float* b2     = (const float*)d_in[16];
    float* out = (float*)d_out;
    float* ws = (float*)d_ws;

    // workspace layout (floats).  total = 43,011,232 floats = 172.0 MB
    float* h_p    = ws;                        // 16,777,216
    float* e_p    = h_p + 16777216;            // 4,915,200
    float* xwc0_p = e_p + 4915200;             // 6,291,456  (chunk, dir0)
    float* xwc1_p = xwc0_p + 6291456;          // 6,291,456  (chunk, dir1)
    float* Wp_p   = xwc1_p + 6291456;          // 1,572,864  (packed Whh, 2 dirs)
    float* Wt0_p  = Wp_p + 1572864;            // 460,800
    float* Wt1_p  = Wt0_p + 460800;            // 460,800
    float* pad_p  = Wt1_p + 460800;            // 1,700,000  (res alias headroom)
    float* bc0_p  = pad_p + 1700000;           // 1,536
    float* bc1_p  = bc0_p + 1536;              // 1,536
    float* W1at_p = bc1_p + 1536;              // 262,144
    float* tg_p   = W1at_p + 262144;           // 65,536
    float* t2_p   = tg_p + 65536;              // 16,384
    float* beta_p = t2_p + 16384;              // 4,194,304
    // aliases into dead-after-GRU regions:
    float* ot_p   = e_p;                       // 4,194,304 <= 4,915,200
    float* res_p  = xwc0_p;                    // 16,777,216 <= xwc0+xwc1+Wp+Wt0+Wt1+pad

    if (ws_size < (size_t)43011232 * 4) return;  // refuse to overflow scratch

    // 1. embedding + renorm
    k_embed<<<BS_, 128, 0, stream>>>(x, emb, e_p);
    // 2. one-time weight preps
    k_prep_w1<<<256, 256, 0, stream>>>(W1, W1at_p);
    k_prep_dir<<<512, 256, 0, stream>>>(Wihf, bihf, Wt0_p, bc0_p);
    k_prep_dir<<<512, 256, 0, stream>>>(Wihb, bihb, Wt1_p, bc1_p);
    k_pack_whh<<<512, 256, 0, stream>>>(Whhf, Wp_p);
    k_pack_whh<<<512, 256, 0, stream>>>(Whhb, Wp_p + 786432);
    // 3. chunked: project both dirs' 64-pos windows, then fused 2-dir GRU
    for (int c = 0; c < NCHK; ++c) {
        k_gemm128<20, 1><<<dim3(12, 32, 1), 256, 0, stream>>>(
            e_p, ED, 0, Wt0_p, G3, 0, xwc0_p, G3, 0, BB * CHK, G3, ED,
            bc0_p, nullptr, CHK * c);
        k_gemm128<20, 1><<<dim3(12, 32, 1), 256, 0, stream>>>(
            e_p, ED, 0, Wt1_p, G3, 0, xwc1_p, G3, 0, BB * CHK, G3, ED,
            bc1_p, nullptr, 192 - CHK * c);
        k_gru_priv2<<<128, 768, 0, stream>>>(xwc0_p, xwc1_p, Wp_p, bhhf, bhhb,
                                             h_p, c);
    }
    // 4. target span mean
    k_target<<<BB, 256, 0, stream>>>(h_p, tstart, tend, tg_p);
    // 5. tmp2[b,a] = b1 + target . W1[:,1024:]
    k_tmp2<<<BB, 256, 0, stream>>>(tg_p, W1, b1, t2_p);
    // 6. o = tanh(h @ W1a^T + tmp2)   [16384, 256]  (o reuses beta slot? no: own)
    //    o written into ot-source buffer first (e region is free now)
    k_gemm128<16, 2><<<dim3(2, 128, 1), 256, 0, stream>>>(
        h_p, 1024, 0, W1at_p, ATT_, 0, res_p, ATT_, 0, BS_, ATT_, 1024,
        nullptr, t2_p, -1);   // o lives temporarily at res_p (16.7M region)
    // 7. transpose o -> ot[b][a][s]
    k_transpose_o<<<dim3(8, 8, BB), 256, 0, stream>>>(res_p, ot_p);
    // 8. beta[b][k][s] = u @ ot[b]
    k_gemm128<16, 0><<<dim3(2, 2, BB), 256, 0, stream>>>(
        u, ATT_, 0, ot_p, ATT_, 65536, beta_p, ATT_, 65536, ATT_, ATT_, ATT_,
        nullptr, nullptr, -1);
    // 9. softmax over s (in place)
    k_softmax<<<BS_, 256, 0, stream>>>(beta_p);
    // 10. result[b][k][h] = alfa[b] @ h[b]   (res_p free again after step 7/8)
    k_gemm128<16, 0><<<dim3(8, 2, BB), 256, 0, stream>>>(
        beta_p, ATT_, 65536, h_p, 1024, 262144, res_p, 1024, 262144,
        ATT_, 1024, ATT_, nullptr, nullptr, -1);
    // 11. final linear
    k_final<<<BS_, 256, 0, stream>>>(res_p, W2, b2, out);
}

// Round 8
// 5697.953 us; speedup vs baseline: 4.0575x; 1.2970x over previous
//
#include <hip/hip_runtime.h>
#include <math.h>

// Problem constants
#define BB   64
#define SS   256
#define ED   300
#define HH   512
#define G3   1536   // 3*H (one direction)
#define ATT_ 256
#define BS_  16384  // BB*SS
#define CHK  64     // timesteps per chunk
#define NCHK 4

// ---------------------------------------------------------------------------
// K1: embedding gather + max-norm renorm.  one block per (b,s) row, 128 thr
// ---------------------------------------------------------------------------
__global__ void k_embed(const int* __restrict__ x, const float* __restrict__ emb,
                        float* __restrict__ e) {
    int row = blockIdx.x;
    int tok = x[row];
    const float* src = emb + (size_t)tok * ED;
    float* dst = e + (size_t)row * ED;
    int tid = threadIdx.x;  // 128
    float v[3];
    float ss = 0.f;
#pragma unroll
    for (int i = 0; i < 3; ++i) {
        int k = tid + i * 128;
        float t = (k < ED) ? src[k] : 0.f;
        v[i] = t;
        ss += t * t;
    }
    for (int off = 32; off > 0; off >>= 1) ss += __shfl_xor(ss, off, 64);
    __shared__ float red[2];
    if ((tid & 63) == 0) red[tid >> 6] = ss;
    __syncthreads();
    float nrm = sqrtf(red[0] + red[1]);
    float scale = fminf(1.0f, 5.0f / (nrm + 1e-7f));
#pragma unroll
    for (int i = 0; i < 3; ++i) {
        int k = tid + i * 128;
        if (k < ED) dst[k] = v[i] * scale;
    }
}

// ---------------------------------------------------------------------------
// K_prep_dir: Wt[300][1536] = Wih_dir^T, bc[1536] = bih_dir  (coalesced reads)
// ---------------------------------------------------------------------------
__global__ void k_prep_dir(const float* __restrict__ Wih, const float* __restrict__ bih,
                           float* __restrict__ Wt, float* __restrict__ bc) {
    int idx = blockIdx.x * blockDim.x + threadIdx.x;
    int stride = gridDim.x * blockDim.x;
    for (int i = idx; i < ED * G3; i += stride) {
        int n = i / ED, k = i - n * ED;
        Wt[(size_t)k * G3 + n] = Wih[i];
    }
    for (int i = idx; i < G3; i += stride) bc[i] = bih[i];
}

// K_prep_w1: W1at[1024][256] = transpose of W1[:, :1024]  (coalesced reads)
__global__ void k_prep_w1(const float* __restrict__ W1, float* __restrict__ W1at) {
    int idx = blockIdx.x * blockDim.x + threadIdx.x;
    int stride = gridDim.x * blockDim.x;
    for (int i = idx; i < 1024 * ATT_; i += stride) {
        int n = i >> 10, k = i & 1023;
        W1at[(size_t)k * ATT_ + n] = W1[(size_t)n * 2048 + k];
    }
}

// K_pack_whh2: pack one dir's Whh into pair-split lane-dense layout.
// Wq[half][kq][row=0..767][e=0..3], strides: half 393216, kq 3072, row 4.
// row r of half h: gate g=r/256, unit u = h*256 + r%256; Whh row = g*512+u.
__global__ void k_pack_whh2(const float* __restrict__ Whh, float* __restrict__ Wq) {
    int idx = blockIdx.x * blockDim.x + threadIdx.x;
    int stride = gridDim.x * blockDim.x;
    for (int i = idx; i < 2 * 128 * 768 * 4; i += stride) {
        int half = i / 393216;
        int rem  = i - half * 393216;
        int kq   = rem / 3072;
        int r2   = rem - kq * 3072;
        int row  = r2 >> 2;
        int e    = r2 & 3;
        int g    = row >> 8;
        int u    = half * 256 + (row & 255);
        Wq[i] = Whh[((size_t)g * 512 + u) * 512 + kq * 4 + e];
    }
}

// ---------------------------------------------------------------------------
// fp32 GEMM, 128x128 tile, 256 threads, 8x8 per thread, float4 LDS reads.
// spos >= 0: A-row r maps to source row (r/64)*256 + spos + (r%64)
// EPI: 0 = none, 1 = +bias[n], 2 = tanh(acc + bias2[(row>>8)*256 + n])
// ---------------------------------------------------------------------------
#define BSKEW(n) ((n) + (((n) >> 5) << 2))

template <int KT, int EPI>
__global__ void __launch_bounds__(256) k_gemm128(
    const float* __restrict__ A, int lda, long strideA,
    const float* __restrict__ Bm, int ldb, long strideB,
    float* __restrict__ C, int ldc, long strideC,
    int M, int N, int K,
    const float* __restrict__ bias, const float* __restrict__ bias2,
    int spos) {
    __shared__ float As[KT * 132];
    __shared__ float Bs[KT * 144];
    const int tid = threadIdx.x;
    const int tx = tid & 15, ty = tid >> 4;
    const int mbase = blockIdx.y * 128, nbase = blockIdx.x * 128;
    const float* Ab = A + (long)blockIdx.z * strideA;
    const float* Bb = Bm + (long)blockIdx.z * strideB;
    float* Cb = C + (long)blockIdx.z * strideC;
    float acc[8][8] = {};
    const int bgrp = tx * 8 + ((tx >> 2) << 2);
    for (int k0 = 0; k0 < K; k0 += KT) {
        for (int i = tid; i < 128 * KT; i += 256) {
            int r = i / KT, c = i % KT;
            int row = mbase + r;
            int arow = (spos >= 0) ? ((row >> 6) * 256 + spos + (row & 63)) : row;
            As[c * 132 + r] = Ab[(size_t)arow * lda + k0 + c];
        }
        for (int i = tid; i < KT * 128; i += 256) {
            int kk = i >> 7, n = i & 127;
            Bs[kk * 144 + BSKEW(n)] = Bb[(size_t)(k0 + kk) * ldb + nbase + n];
        }
        __syncthreads();
#pragma unroll
        for (int kk = 0; kk < KT; ++kk) {
            const float4* pa = (const float4*)&As[kk * 132 + ty * 8];
            float4 a0 = pa[0], a1 = pa[1];
            const float4* pb = (const float4*)&Bs[kk * 144 + bgrp];
            float4 b0 = pb[0], b1 = pb[1];
            float av[8] = {a0.x, a0.y, a0.z, a0.w, a1.x, a1.y, a1.z, a1.w};
            float bv[8] = {b0.x, b0.y, b0.z, b0.w, b1.x, b1.y, b1.z, b1.w};
#pragma unroll
            for (int i = 0; i < 8; ++i)
#pragma unroll
                for (int j = 0; j < 8; ++j) acc[i][j] += av[i] * bv[j];
        }
        __syncthreads();
    }
#pragma unroll
    for (int i = 0; i < 8; ++i) {
        int row = mbase + ty * 8 + i;
        float vout[8];
#pragma unroll
        for (int j = 0; j < 8; ++j) {
            int col = nbase + tx * 8 + j;
            float v = acc[i][j];
            if (EPI == 1) v += bias[col];
            if (EPI == 2) v = tanhf(v + bias2[(size_t)(row >> 8) * ATT_ + col]);
            vout[j] = v;
        }
        float4* cp = (float4*)&Cb[(size_t)row * ldc + nbase + tx * 8];
        cp[0] = make_float4(vout[0], vout[1], vout[2], vout[3]);
        cp[1] = make_float4(vout[4], vout[5], vout[6], vout[7]);
    }
}

// ---------------------------------------------------------------------------
// GRU helpers
// ---------------------------------------------------------------------------
__device__ __forceinline__ float sigmoidf_(float v) { return 1.f / (1.f + expf(-v)); }

// ---------------------------------------------------------------------------
// Pair-split block-private GRU, chunked over time.
// 256 blocks = 2 per (dir,b): half = bid&1, b = (bid>>1)&63, dir = bid>>7.
// Each block streams HALF the weights (1.5 MB/step, its 256 units x 3 gates),
// computes its units' gate update, and exchanges its 256 h values with the
// partner through IC via RELAXED atomics + one RELEASE flag (NO acquire ops
// anywhere -> L2 weight stream is never invalidated).  hx double-buffered by
// step parity.  Matvec does own-k half first (self-produced h) to hide the
// exchange latency under 5 us of weight streaming.
// ---------------------------------------------------------------------------
__global__ void __launch_bounds__(768)
k_gru_pair(const float* __restrict__ xw0, const float* __restrict__ xw1,
           const float* __restrict__ Wq,   // packed, [dir][half][kq][768][4]
           const float* __restrict__ bhhf, const float* __restrict__ bhhb,
           float* __restrict__ h_all,
           float* __restrict__ hx,         // [parity][dir][b][half][256]
           unsigned* __restrict__ flg,     // [(dir*64+b)*2+half] * 32 pad
           int c) {
    const int bid  = blockIdx.x;
    const int dir  = bid >> 7;
    const int b    = (bid >> 1) & 63;
    const int half = bid & 1;
    const int tid  = threadIdx.x;
    const float* __restrict__ xwc = dir ? xw1 : xw0;
    const float* __restrict__ bhh = dir ? bhhb : bhhf;
    const float4* __restrict__ wq4 =
        (const float4*)Wq + (size_t)(dir * 2 + half) * 98304;
    const int pbase = (half ^ 1) * 256;        // partner units base in hs
    const int fi = ((dir * 64 + b) * 2 + half) * 32;
    const int fp = ((dir * 64 + b) * 2 + (half ^ 1)) * 32;
    __shared__ __align__(16) float hs[512];
    __shared__ float gact[768];

    if (c == 0) {
        for (int t = tid; t < 512; t += 768) hs[t] = 0.f;
    } else {
        const int prevpos = dir ? (256 - CHK * c) : (CHK * c - 1);
        for (int t = tid; t < 512; t += 768)
            hs[t] = h_all[((size_t)b * 256 + prevpos) * 1024 + dir * 512 + t];
    }
    // per-unit constants for gate-update threads
    float b0 = 0.f, b1 = 0.f, b2 = 0.f;
    const int u = half * 256 + (tid & 255);    // unit for tid<256
    if (tid < 256) { b0 = bhh[u]; b1 = bhh[512 + u]; b2 = bhh[1024 + u]; }
    __syncthreads();
    const float4* __restrict__ hs4 = (const float4*)hs;
    const int ok0 = half * 64;                  // own-k  quads [ok0, ok0+64)
    const int pk0 = (half ^ 1) * 64;            // partner-k quads

    for (int j = 0; j < CHK; ++j) {
        const int gi  = c * CHK + j;
        const int pos = dir ? (255 - gi) : gi;
        const int crow = b * CHK + (dir ? (CHK - 1 - j) : j);
        // prefetch phase-2 inputs early (independent of h)
        float xr = 0.f, xz = 0.f, xn = 0.f;
        if (tid < 256) {
            const float* __restrict__ xrow = xwc + (size_t)crow * 1536;
            xr = xrow[u]; xz = xrow[512 + u]; xn = xrow[1024 + u];
        }
        if (gi > 0) {
            float acc = 0.f;
            if (j > 0) {
                // phase A: own-k half (h produced by this block last step)
#pragma unroll 4
                for (int kq = ok0; kq < ok0 + 64; ++kq) {
                    float4 h4 = hs4[kq];
                    float4 w = wq4[(size_t)kq * 768 + tid];
                    acc += h4.x * w.x + h4.y * w.y + h4.z * w.z + h4.w * w.w;
                }
                // wait for partner's h (released after its step gi-1)
                if (tid == 0) {
                    while (__hip_atomic_load(&flg[fp], __ATOMIC_RELAXED,
                                             __HIP_MEMORY_SCOPE_AGENT) < (unsigned)gi)
                        __builtin_amdgcn_s_sleep(1);
                }
                __syncthreads();
                if (tid < 256) {
                    const float* src = hx + ((size_t)((gi - 1) & 1) * 128 +
                                             dir * 64 + b) * 512 +
                                       (half ^ 1) * 256 + tid;
                    hs[pbase + tid] = __hip_atomic_load(src, __ATOMIC_RELAXED,
                                                        __HIP_MEMORY_SCOPE_AGENT);
                }
                __syncthreads();
                // phase B: partner-k half
#pragma unroll 4
                for (int kq = pk0; kq < pk0 + 64; ++kq) {
                    float4 h4 = hs4[kq];
                    float4 w = wq4[(size_t)kq * 768 + tid];
                    acc += h4.x * w.x + h4.y * w.y + h4.z * w.z + h4.w * w.w;
                }
            } else {
                // chunk start (c>0): hs fully loaded from h_all
#pragma unroll 4
                for (int kq = 0; kq < 128; ++kq) {
                    float4 h4 = hs4[kq];
                    float4 w = wq4[(size_t)kq * 768 + tid];
                    acc += h4.x * w.x + h4.y * w.y + h4.z * w.z + h4.w * w.w;
                }
            }
            gact[tid] = acc;
            __syncthreads();
        }
        if (tid < 256) {
            float hr = (gi > 0) ? gact[tid] : 0.f;
            float hz = (gi > 0) ? gact[256 + tid] : 0.f;
            float hn = (gi > 0) ? gact[512 + tid] : 0.f;
            float r = sigmoidf_(xr + b0 + hr);
            float z = sigmoidf_(xz + b1 + hz);
            float n = tanhf(xn + r * (b2 + hn));
            float h = (1.f - z) * n + z * hs[u];
            hs[u] = h;
            __hip_atomic_store(&h_all[((size_t)b * 256 + pos) * 1024 +
                                      dir * 512 + u],
                               h, __ATOMIC_RELAXED, __HIP_MEMORY_SCOPE_AGENT);
            __hip_atomic_store(&hx[((size_t)(gi & 1) * 128 + dir * 64 + b) * 512 +
                                   half * 256 + tid],
                               h, __ATOMIC_RELAXED, __HIP_MEMORY_SCOPE_AGENT);
        }
        __syncthreads();   // hx stores drained (barrier implies vmcnt(0))
        if (tid == 0)
            __hip_atomic_store(&flg[fi], (unsigned)(gi + 1), __ATOMIC_RELEASE,
                               __HIP_MEMORY_SCOPE_AGENT);
    }
}

// ---------------------------------------------------------------------------
// K4: masked mean over target span -> target[b, 1024]
// ---------------------------------------------------------------------------
__global__ void k_target(const float* __restrict__ h_all, const int* __restrict__ ts,
                         const int* __restrict__ te, float* __restrict__ target) {
    int b = blockIdx.x;
    int tid = threadIdx.x;  // 256
    int s0 = ts[b], s1 = te[b];
    float inv = 1.f / (float)(s1 - s0 + 1);
    for (int d = tid; d < 1024; d += 256) {
        float acc = 0.f;
        for (int s = s0; s <= s1; ++s) acc += h_all[((size_t)b * 256 + s) * 1024 + d];
        target[(size_t)b * 1024 + d] = acc * inv;
    }
}

// ---------------------------------------------------------------------------
// K4b: tmp2[b,a] = b1[a] + target[b,:] . W1[a, 1024:2048]
// ---------------------------------------------------------------------------
__global__ void k_tmp2(const float* __restrict__ target, const float* __restrict__ W1,
                       const float* __restrict__ b1, float* __restrict__ tmp2) {
    int b = blockIdx.x;
    int a = threadIdx.x;  // 256
    __shared__ float tg[1024];
    for (int d = a; d < 1024; d += 256) tg[d] = target[(size_t)b * 1024 + d];
    __syncthreads();
    const float4* wrow = (const float4*)(W1 + (size_t)a * 2048 + 1024);
    const float4* tg4 = (const float4*)tg;
    float acc = b1[a];
    for (int k = 0; k < 256; ++k) {
        float4 w = wrow[k], t = tg4[k];
        acc += w.x * t.x + w.y * t.y + w.z * t.z + w.w * t.w;
    }
    tmp2[(size_t)b * ATT_ + a] = acc;
}

// ---------------------------------------------------------------------------
// transpose o[b][s][a] -> ot[b][a][s]
// ---------------------------------------------------------------------------
__global__ void k_transpose_o(const float* __restrict__ o, float* __restrict__ ot) {
    int b = blockIdx.z;
    __shared__ float t[32][33];
    int a0 = blockIdx.x * 32, s0 = blockIdx.y * 32;
    int tx = threadIdx.x & 31, ty = threadIdx.x >> 5;  // 32x8
    for (int i = ty; i < 32; i += 8)
        t[i][tx] = o[((size_t)b * 256 + s0 + i) * 256 + a0 + tx];
    __syncthreads();
    for (int i = ty; i < 32; i += 8)
        ot[((size_t)b * 256 + a0 + i) * 256 + s0 + tx] = t[tx][i];
}

// ---------------------------------------------------------------------------
// softmax over last axis, in place.  one block per (b,k) row of 256.
// ---------------------------------------------------------------------------
__global__ void k_softmax(float* __restrict__ beta) {
    int row = blockIdx.x;
    float* p = beta + (size_t)row * 256;
    int tid = threadIdx.x;  // 256
    float v = p[tid];
    float m = v;
    for (int off = 32; off > 0; off >>= 1) m = fmaxf(m, __shfl_xor(m, off, 64));
    __shared__ float red[4];
    if ((tid & 63) == 0) red[tid >> 6] = m;
    __syncthreads();
    m = fmaxf(fmaxf(red[0], red[1]), fmaxf(red[2], red[3]));
    float e = expf(v - m);
    float ssum = e;
    for (int off = 32; off > 0; off >>= 1) ssum += __shfl_xor(ssum, off, 64);
    __shared__ float red2[4];
    if ((tid & 63) == 0) red2[tid >> 6] = ssum;
    __syncthreads();
    float tot = red2[0] + red2[1] + red2[2] + red2[3];
    p[tid] = e / tot;
}

// ---------------------------------------------------------------------------
// final: out[row, 0:3] = result[row,:] . W2[l,:] + b2[l]
// ---------------------------------------------------------------------------
__global__ void k_final(const float* __restrict__ result, const float* __restrict__ W2,
                        const float* __restrict__ b2, float* __restrict__ out) {
    int row = blockIdx.x;
    int tid = threadIdx.x;  // 256
    const float* r = result + (size_t)row * 1024;
    float a0 = 0.f, a1 = 0.f, a2 = 0.f;
    for (int h = tid; h < 1024; h += 256) {
        float rv = r[h];
        a0 += rv * W2[h];
        a1 += rv * W2[1024 + h];
        a2 += rv * W2[2048 + h];
    }
    for (int off = 32; off > 0; off >>= 1) {
        a0 += __shfl_xor(a0, off, 64);
        a1 += __shfl_xor(a1, off, 64);
        a2 += __shfl_xor(a2, off, 64);
    }
    __shared__ float red[4][3];
    if ((tid & 63) == 0) {
        red[tid >> 6][0] = a0; red[tid >> 6][1] = a1; red[tid >> 6][2] = a2;
    }
    __syncthreads();
    if (tid < 3) {
        float s = red[0][tid] + red[1][tid] + red[2][tid] + red[3][tid];
        out[(size_t)row * 3 + tid] = s + b2[tid];
    }
}

// ---------------------------------------------------------------------------
extern "C" void kernel_launch(void* const* d_in, const int* in_sizes, int n_in,
                              void* d_out, int out_size, void* d_ws, size_t ws_size,
                              hipStream_t stream) {
    const int*   x      = (const int*)d_in[0];
    const int*   tstart = (const int*)d_in[1];
    const int*   tend   = (const int*)d_in[2];
    const float* emb    = (const float*)d_in[3];
    const float* Wihf   = (const float*)d_in[4];
    const float* Whhf   = (const float*)d_in[5];
    const float* bihf   = (const float*)d_in[6];
    const float* bhhf   = (const float*)d_in[7];
    const float* Wihb   = (const float*)d_in[8];
    const float* Whhb   = (const float*)d_in[9];
    const float* bihb   = (const float*)d_in[10];
    const float* bhhb   = (const float*)d_in[11];
    const float* W1     = (const float*)d_in[12];
    const float* b1     = (const float*)d_in[13];
    const float* u      = (const float*)d_in[14];
    const float* W2     = (const float*)d_in[15];
    const float* b2     = (const float*)d_in[16];
    float* out = (float*)d_out;
    float* ws = (float*)d_ws;

    // workspace layout (floats).  total = 43,158,688 floats = 172.6 MB
    float* h_p    = ws;                        // 16,777,216
    float* e_p    = h_p + 16777216;            // 4,915,200
    float* xwc0_p = e_p + 4915200;             // 6,291,456  (chunk, dir0)
    float* xwc1_p = xwc0_p + 6291456;          // 6,291,456  (chunk, dir1)
    float* Wq_p   = xwc1_p + 6291456;          // 1,572,864  (packed Whh, 2 dirs)
    float* Wt0_p  = Wq_p + 1572864;            // 460,800
    float* Wt1_p  = Wt0_p + 460800;            // 460,800
    float* pad_p  = Wt1_p + 460800;            // 1,700,000  (res alias headroom)
    float* bc0_p  = pad_p + 1700000;           // 1,536
    float* bc1_p  = bc0_p + 1536;              // 1,536
    float* W1at_p = bc1_p + 1536;              // 262,144
    float* tg_p   = W1at_p + 262144;           // 65,536
    float* t2_p   = tg_p + 65536;              // 16,384
    float* beta_p = t2_p + 16384;              // 4,194,304
    float* hx_p   = beta_p + 4194304;          // 131,072  (2 parity x 128 x 512)
    unsigned* flg_p = (unsigned*)(hx_p + 131072);  // 16,384 uints
    // aliases into dead-after-GRU regions:
    float* ot_p   = e_p;                       // 4,194,304 <= 4,915,200
    float* res_p  = xwc0_p;                    // 16,777,216 spans xwc0..pad

    if (ws_size < (size_t)43158688 * 4) return;  // refuse to overflow scratch

    // 0. zero pair flags (every call / graph replay)
    hipMemsetAsync(flg_p, 0, 16384 * sizeof(unsigned), stream);
    // 1. embedding + renorm
    k_embed<<<BS_, 128, 0, stream>>>(x, emb, e_p);
    // 2. one-time weight preps
    k_prep_w1<<<256, 256, 0, stream>>>(W1, W1at_p);
    k_prep_dir<<<512, 256, 0, stream>>>(Wihf, bihf, Wt0_p, bc0_p);
    k_prep_dir<<<512, 256, 0, stream>>>(Wihb, bihb, Wt1_p, bc1_p);
    k_pack_whh2<<<512, 256, 0, stream>>>(Whhf, Wq_p);
    k_pack_whh2<<<512, 256, 0, stream>>>(Whhb, Wq_p + 786432);
    // 3. chunked: project both dirs' 64-pos windows, then pair-split GRU
    for (int c = 0; c < NCHK; ++c) {
        k_gemm128<20, 1><<<dim3(12, 32, 1), 256, 0, stream>>>(
            e_p, ED, 0, Wt0_p, G3, 0, xwc0_p, G3, 0, BB * CHK, G3, ED,
            bc0_p, nullptr, CHK * c);
        k_gemm128<20, 1><<<dim3(12, 32, 1), 256, 0, stream>>>(
            e_p, ED, 0, Wt1_p, G3, 0, xwc1_p, G3, 0, BB * CHK, G3, ED,
            bc1_p, nullptr, 192 - CHK * c);
        k_gru_pair<<<256, 768, 0, stream>>>(xwc0_p, xwc1_p, Wq_p, bhhf, bhhb,
                                            h_p, hx_p, flg_p, c);
    }
    // 4. target span mean
    k_target<<<BB, 256, 0, stream>>>(h_p, tstart, tend, tg_p);
    // 5. tmp2[b,a] = b1 + target . W1[:,1024:]
    k_tmp2<<<BB, 256, 0, stream>>>(tg_p, W1, b1, t2_p);
    // 6. o = tanh(h @ W1a^T + tmp2)   [16384, 256]  (o at res_p temporarily)
    k_gemm128<16, 2><<<dim3(2, 128, 1), 256, 0, stream>>>(
        h_p, 1024, 0, W1at_p, ATT_, 0, res_p, ATT_, 0, BS_, ATT_, 1024,
        nullptr, t2_p, -1);
    // 7. transpose o -> ot[b][a][s]
    k_transpose_o<<<dim3(8, 8, BB), 256, 0, stream>>>(res_p, ot_p);
    // 8. beta[b][k][s] = u @ ot[b]
    k_gemm128<16, 0><<<dim3(2, 2, BB), 256, 0, stream>>>(
        u, ATT_, 0, ot_p, ATT_, 65536, beta_p, ATT_, 65536, ATT_, ATT_, ATT_,
        nullptr, nullptr, -1);
    // 9. softmax over s (in place)
    k_softmax<<<BS_, 256, 0, stream>>>(beta_p);
    // 10. result[b][k][h] = alfa[b] @ h[b]
    k_gemm128<16, 0><<<dim3(8, 2, BB), 256, 0, stream>>>(
        beta_p, ATT_, 65536, h_p, 1024, 262144, res_p, 1024, 262144,
        ATT_, 1024, ATT_, nullptr, nullptr, -1);
    // 11. final linear
    k_final<<<BS_, 256, 0, stream>>>(res_p, W2, b2, out);
}

// Round 9
// 5645.121 us; speedup vs baseline: 4.0955x; 1.0094x over previous
//
#include <hip/hip_runtime.h>
#include <math.h>

// Problem constants
#define BB   64
#define SS   256
#define ED   300
#define EDP  304    // padded K for input projection (zeros in 300..303)
#define HH   512
#define G3   1536   // 3*H (one direction)
#define ATT_ 256
#define BS_  16384  // BB*SS
#define CHK  64     // timesteps per chunk
#define NCHK 4

// ---------------------------------------------------------------------------
// K1: embedding gather + max-norm renorm.  one block per (b,s) row, 128 thr.
// Writes padded rows of EDP (cols 300..303 = 0) every call (poison-safe).
// ---------------------------------------------------------------------------
__global__ void k_embed(const int* __restrict__ x, const float* __restrict__ emb,
                        float* __restrict__ e) {
    int row = blockIdx.x;
    int tok = x[row];
    const float* src = emb + (size_t)tok * ED;
    float* dst = e + (size_t)row * EDP;
    int tid = threadIdx.x;  // 128
    float v[3];
    float ss = 0.f;
#pragma unroll
    for (int i = 0; i < 3; ++i) {
        int k = tid + i * 128;
        float t = (k < ED) ? src[k] : 0.f;
        v[i] = t;
        ss += t * t;
    }
    for (int off = 32; off > 0; off >>= 1) ss += __shfl_xor(ss, off, 64);
    __shared__ float red[2];
    if ((tid & 63) == 0) red[tid >> 6] = ss;
    __syncthreads();
    float nrm = sqrtf(red[0] + red[1]);
    float scale = fminf(1.0f, 5.0f / (nrm + 1e-7f));
#pragma unroll
    for (int i = 0; i < 3; ++i) {
        int k = tid + i * 128;
        if (k < EDP) dst[k] = (k < ED) ? v[i] * scale : 0.f;
    }
}

// ---------------------------------------------------------------------------
// K_prep_dir: Wt[EDP][1536] = Wih_dir^T (rows 300..303 zero), bc = bih_dir
// ---------------------------------------------------------------------------
__global__ void k_prep_dir(const float* __restrict__ Wih, const float* __restrict__ bih,
                           float* __restrict__ Wt, float* __restrict__ bc) {
    int idx = blockIdx.x * blockDim.x + threadIdx.x;
    int stride = gridDim.x * blockDim.x;
    for (int i = idx; i < ED * G3; i += stride) {
        int n = i / ED, k = i - n * ED;
        Wt[(size_t)k * G3 + n] = Wih[i];
    }
    for (int i = idx; i < 4 * G3; i += stride)
        Wt[(size_t)(ED + i / G3) * G3 + (i % G3)] = 0.f;
    for (int i = idx; i < G3; i += stride) bc[i] = bih[i];
}

// K_prep_w1: W1at[1024][256] = transpose of W1[:, :1024]  (coalesced reads)
__global__ void k_prep_w1(const float* __restrict__ W1, float* __restrict__ W1at) {
    int idx = blockIdx.x * blockDim.x + threadIdx.x;
    int stride = gridDim.x * blockDim.x;
    for (int i = idx; i < 1024 * ATT_; i += stride) {
        int n = i >> 10, k = i & 1023;
        W1at[(size_t)k * ATT_ + n] = W1[(size_t)n * 2048 + k];
    }
}

// K_pack_whh2: pack one dir's Whh into pair-split lane-dense layout.
// Wq[half][kq][row=0..767][e=0..3]; row r of half h: gate g=r/256,
// unit u = h*256 + r%256; Whh row = g*512+u.
__global__ void k_pack_whh2(const float* __restrict__ Whh, float* __restrict__ Wq) {
    int idx = blockIdx.x * blockDim.x + threadIdx.x;
    int stride = gridDim.x * blockDim.x;
    for (int i = idx; i < 2 * 128 * 768 * 4; i += stride) {
        int half = i / 393216;
        int rem  = i - half * 393216;
        int kq   = rem / 3072;
        int r2   = rem - kq * 3072;
        int row  = r2 >> 2;
        int e    = r2 & 3;
        int g    = row >> 8;
        int u    = half * 256 + (row & 255);
        Wq[i] = Whh[((size_t)g * 512 + u) * 512 + kq * 4 + e];
    }
}

// ---------------------------------------------------------------------------
// fp32 GEMM, 128x128 tile, 256 threads, 8x8 per thread, float4 LDS reads.
// spos >= 0: A-row r maps to source row (r/64)*256 + spos + (r%64)
// EPI: 0 = none, 1 = +bias[n], 2 = tanh(acc + bias2[(row>>8)*256 + n])
// ---------------------------------------------------------------------------
#define BSKEW(n) ((n) + (((n) >> 5) << 2))

template <int KT, int EPI>
__global__ void __launch_bounds__(256) k_gemm128(
    const float* __restrict__ A, int lda, long strideA,
    const float* __restrict__ Bm, int ldb, long strideB,
    float* __restrict__ C, int ldc, long strideC,
    int M, int N, int K,
    const float* __restrict__ bias, const float* __restrict__ bias2,
    int spos) {
    __shared__ float As[KT * 132];
    __shared__ float Bs[KT * 144];
    const int tid = threadIdx.x;
    const int tx = tid & 15, ty = tid >> 4;
    const int mbase = blockIdx.y * 128, nbase = blockIdx.x * 128;
    const float* Ab = A + (long)blockIdx.z * strideA;
    const float* Bb = Bm + (long)blockIdx.z * strideB;
    float* Cb = C + (long)blockIdx.z * strideC;
    float acc[8][8] = {};
    const int bgrp = tx * 8 + ((tx >> 2) << 2);
    for (int k0 = 0; k0 < K; k0 += KT) {
        for (int i = tid; i < 128 * KT; i += 256) {
            int r = i / KT, c = i % KT;
            int row = mbase + r;
            int arow = (spos >= 0) ? ((row >> 6) * 256 + spos + (row & 63)) : row;
            As[c * 132 + r] = Ab[(size_t)arow * lda + k0 + c];
        }
        for (int i = tid; i < KT * 128; i += 256) {
            int kk = i >> 7, n = i & 127;
            Bs[kk * 144 + BSKEW(n)] = Bb[(size_t)(k0 + kk) * ldb + nbase + n];
        }
        __syncthreads();
#pragma unroll
        for (int kk = 0; kk < KT; ++kk) {
            const float4* pa = (const float4*)&As[kk * 132 + ty * 8];
            float4 a0 = pa[0], a1 = pa[1];
            const float4* pb = (const float4*)&Bs[kk * 144 + bgrp];
            float4 b0 = pb[0], b1 = pb[1];
            float av[8] = {a0.x, a0.y, a0.z, a0.w, a1.x, a1.y, a1.z, a1.w};
            float bv[8] = {b0.x, b0.y, b0.z, b0.w, b1.x, b1.y, b1.z, b1.w};
#pragma unroll
            for (int i = 0; i < 8; ++i)
#pragma unroll
                for (int j = 0; j < 8; ++j) acc[i][j] += av[i] * bv[j];
        }
        __syncthreads();
    }
#pragma unroll
    for (int i = 0; i < 8; ++i) {
        int row = mbase + ty * 8 + i;
        float vout[8];
#pragma unroll
        for (int j = 0; j < 8; ++j) {
            int col = nbase + tx * 8 + j;
            float v = acc[i][j];
            if (EPI == 1) v += bias[col];
            if (EPI == 2) v = tanhf(v + bias2[(size_t)(row >> 8) * ATT_ + col]);
            vout[j] = v;
        }
        float4* cp = (float4*)&Cb[(size_t)row * ldc + nbase + tx * 8];
        cp[0] = make_float4(vout[0], vout[1], vout[2], vout[3]);
        cp[1] = make_float4(vout[4], vout[5], vout[6], vout[7]);
    }
}

// ---------------------------------------------------------------------------
// GRU helpers
// ---------------------------------------------------------------------------
__device__ __forceinline__ float sigmoidf_(float v) { return 1.f / (1.f + expf(-v)); }

// ---------------------------------------------------------------------------
// Pair-split block-private GRU, chunked over time.
// 256 blocks = 2 per (dir,b).  Round-9 change: partner flag poll + the 256
// relaxed IC h-loads are hoisted to STEP START, so their latency hides under
// phase A's weight streaming instead of sitting between phase A and phase B.
// ---------------------------------------------------------------------------
__global__ void __launch_bounds__(768)
k_gru_pair(const float* __restrict__ xw0, const float* __restrict__ xw1,
           const float* __restrict__ Wq,   // packed, [dir][half][kq][768][4]
           const float* __restrict__ bhhf, const float* __restrict__ bhhb,
           float* __restrict__ h_all,
           float* __restrict__ hx,         // [parity][dir][b][half][256]
           unsigned* __restrict__ flg,     // [(dir*64+b)*2+half] * 32 pad
           int c) {
    const int bid  = blockIdx.x;
    const int dir  = bid >> 7;
    const int b    = (bid >> 1) & 63;
    const int half = bid & 1;
    const int tid  = threadIdx.x;
    const float* __restrict__ xwc = dir ? xw1 : xw0;
    const float* __restrict__ bhh = dir ? bhhb : bhhf;
    const float4* __restrict__ wq4 =
        (const float4*)Wq + (size_t)(dir * 2 + half) * 98304;
    const int pbase = (half ^ 1) * 256;        // partner units base in hs
    const int fi = ((dir * 64 + b) * 2 + half) * 32;
    const int fp = ((dir * 64 + b) * 2 + (half ^ 1)) * 32;
    __shared__ __align__(16) float hs[512];
    __shared__ float gact[768];

    if (c == 0) {
        for (int t = tid; t < 512; t += 768) hs[t] = 0.f;
    } else {
        const int prevpos = dir ? (256 - CHK * c) : (CHK * c - 1);
        for (int t = tid; t < 512; t += 768)
            hs[t] = h_all[((size_t)b * 256 + prevpos) * 1024 + dir * 512 + t];
    }
    float b0 = 0.f, b1 = 0.f, b2 = 0.f;
    const int u = half * 256 + (tid & 255);    // unit for tid<256
    if (tid < 256) { b0 = bhh[u]; b1 = bhh[512 + u]; b2 = bhh[1024 + u]; }
    __syncthreads();
    const float4* __restrict__ hs4 = (const float4*)hs;
    const int ok0 = half * 64;                  // own-k  quads
    const int pk0 = (half ^ 1) * 64;            // partner-k quads

    for (int j = 0; j < CHK; ++j) {
        const int gi  = c * CHK + j;
        const int pos = dir ? (255 - gi) : gi;
        const int crow = b * CHK + (dir ? (CHK - 1 - j) : j);
        // --- hoisted partner exchange: poll flag, issue h loads early ---
        float ph = 0.f;
        if (gi > 0 && j > 0) {
            if (tid == 0) {
                while (__hip_atomic_load(&flg[fp], __ATOMIC_RELAXED,
                                         __HIP_MEMORY_SCOPE_AGENT) < (unsigned)gi)
                    __builtin_amdgcn_s_sleep(1);
            }
            __syncthreads();
            if (tid < 256) {
                const float* src = hx + ((size_t)((gi - 1) & 1) * 128 +
                                         dir * 64 + b) * 512 +
                                   (half ^ 1) * 256 + tid;
                ph = __hip_atomic_load(src, __ATOMIC_RELAXED,
                                       __HIP_MEMORY_SCOPE_AGENT);
            }
        }
        // --- xw prefetch (independent of h) ---
        float xr = 0.f, xz = 0.f, xn = 0.f;
        if (tid < 256) {
            const float* __restrict__ xrow = xwc + (size_t)crow * 1536;
            xr = xrow[u]; xz = xrow[512 + u]; xn = xrow[1024 + u];
        }
        if (gi > 0) {
            float acc = 0.f;
            if (j > 0) {
                // phase A: own-k half (hides the ph load latency)
#pragma unroll 4
                for (int kq = ok0; kq < ok0 + 64; ++kq) {
                    float4 h4 = hs4[kq];
                    float4 w = wq4[(size_t)kq * 768 + tid];
                    acc += h4.x * w.x + h4.y * w.y + h4.z * w.z + h4.w * w.w;
                }
                // deposit partner h, then phase B
                if (tid < 256) hs[pbase + tid] = ph;
                __syncthreads();
#pragma unroll 4
                for (int kq = pk0; kq < pk0 + 64; ++kq) {
                    float4 h4 = hs4[kq];
                    float4 w = wq4[(size_t)kq * 768 + tid];
                    acc += h4.x * w.x + h4.y * w.y + h4.z * w.z + h4.w * w.w;
                }
            } else {
                // chunk start (c>0): hs fully loaded from h_all
#pragma unroll 4
                for (int kq = 0; kq < 128; ++kq) {
                    float4 h4 = hs4[kq];
                    float4 w = wq4[(size_t)kq * 768 + tid];
                    acc += h4.x * w.x + h4.y * w.y + h4.z * w.z + h4.w * w.w;
                }
            }
            gact[tid] = acc;
            __syncthreads();
        }
        if (tid < 256) {
            float hr = (gi > 0) ? gact[tid] : 0.f;
            float hz = (gi > 0) ? gact[256 + tid] : 0.f;
            float hn = (gi > 0) ? gact[512 + tid] : 0.f;
            float r = sigmoidf_(xr + b0 + hr);
            float z = sigmoidf_(xz + b1 + hz);
            float n = tanhf(xn + r * (b2 + hn));
            float h = (1.f - z) * n + z * hs[u];
            hs[u] = h;
            __hip_atomic_store(&h_all[((size_t)b * 256 + pos) * 1024 +
                                      dir * 512 + u],
                               h, __ATOMIC_RELAXED, __HIP_MEMORY_SCOPE_AGENT);
            __hip_atomic_store(&hx[((size_t)(gi & 1) * 128 + dir * 64 + b) * 512 +
                                   half * 256 + tid],
                               h, __ATOMIC_RELAXED, __HIP_MEMORY_SCOPE_AGENT);
        }
        __syncthreads();   // hx stores drained before release
        if (tid == 0)
            __hip_atomic_store(&flg[fi], (unsigned)(gi + 1), __ATOMIC_RELEASE,
                               __HIP_MEMORY_SCOPE_AGENT);
    }
}

// ---------------------------------------------------------------------------
// K4: masked mean over target span -> target[b, 1024]
// ---------------------------------------------------------------------------
__global__ void k_target(const float* __restrict__ h_all, const int* __restrict__ ts,
                         const int* __restrict__ te, float* __restrict__ target) {
    int b = blockIdx.x;
    int tid = threadIdx.x;  // 256
    int s0 = ts[b], s1 = te[b];
    float inv = 1.f / (float)(s1 - s0 + 1);
    for (int d = tid; d < 1024; d += 256) {
        float acc = 0.f;
        for (int s = s0; s <= s1; ++s) acc += h_all[((size_t)b * 256 + s) * 1024 + d];
        target[(size_t)b * 1024 + d] = acc * inv;
    }
}

// ---------------------------------------------------------------------------
// K4b: tmp2[b,a] = b1[a] + target[b,:] . W1[a, 1024:2048]
// ---------------------------------------------------------------------------
__global__ void k_tmp2(const float* __restrict__ target, const float* __restrict__ W1,
                       const float* __restrict__ b1, float* __restrict__ tmp2) {
    int b = blockIdx.x;
    int a = threadIdx.x;  // 256
    __shared__ float tg[1024];
    for (int d = a; d < 1024; d += 256) tg[d] = target[(size_t)b * 1024 + d];
    __syncthreads();
    const float4* wrow = (const float4*)(W1 + (size_t)a * 2048 + 1024);
    const float4* tg4 = (const float4*)tg;
    float acc = b1[a];
    for (int k = 0; k < 256; ++k) {
        float4 w = wrow[k], t = tg4[k];
        acc += w.x * t.x + w.y * t.y + w.z * t.z + w.w * t.w;
    }
    tmp2[(size_t)b * ATT_ + a] = acc;
}

// ---------------------------------------------------------------------------
// transpose o[b][s][a] -> ot[b][a][s]
// ---------------------------------------------------------------------------
__global__ void k_transpose_o(const float* __restrict__ o, float* __restrict__ ot) {
    int b = blockIdx.z;
    __shared__ float t[32][33];
    int a0 = blockIdx.x * 32, s0 = blockIdx.y * 32;
    int tx = threadIdx.x & 31, ty = threadIdx.x >> 5;  // 32x8
    for (int i = ty; i < 32; i += 8)
        t[i][tx] = o[((size_t)b * 256 + s0 + i) * 256 + a0 + tx];
    __syncthreads();
    for (int i = ty; i < 32; i += 8)
        ot[((size_t)b * 256 + a0 + i) * 256 + s0 + tx] = t[tx][i];
}

// ---------------------------------------------------------------------------
// softmax over last axis, in place.  one block per (b,k) row of 256.
// ---------------------------------------------------------------------------
__global__ void k_softmax(float* __restrict__ beta) {
    int row = blockIdx.x;
    float* p = beta + (size_t)row * 256;
    int tid = threadIdx.x;  // 256
    float v = p[tid];
    float m = v;
    for (int off = 32; off > 0; off >>= 1) m = fmaxf(m, __shfl_xor(m, off, 64));
    __shared__ float red[4];
    if ((tid & 63) == 0) red[tid >> 6] = m;
    __syncthreads();
    m = fmaxf(fmaxf(red[0], red[1]), fmaxf(red[2], red[3]));
    float e = expf(v - m);
    float ssum = e;
    for (int off = 32; off > 0; off >>= 1) ssum += __shfl_xor(ssum, off, 64);
    __shared__ float red2[4];
    if ((tid & 63) == 0) red2[tid >> 6] = ssum;
    __syncthreads();
    float tot = red2[0] + red2[1] + red2[2] + red2[3];
    p[tid] = e / tot;
}

// ---------------------------------------------------------------------------
// final: out[row, 0:3] = result[row,:] . W2[l,:] + b2[l]
// ---------------------------------------------------------------------------
__global__ void k_final(const float* __restrict__ result, const float* __restrict__ W2,
                        const float* __restrict__ b2, float* __restrict__ out) {
    int row = blockIdx.x;
    int tid = threadIdx.x;  // 256
    const float* r = result + (size_t)row * 1024;
    float a0 = 0.f, a1 = 0.f, a2 = 0.f;
    for (int h = tid; h < 1024; h += 256) {
        float rv = r[h];
        a0 += rv * W2[h];
        a1 += rv * W2[1024 + h];
        a2 += rv * W2[2048 + h];
    }
    for (int off = 32; off > 0; off >>= 1) {
        a0 += __shfl_xor(a0, off, 64);
        a1 += __shfl_xor(a1, off, 64);
        a2 += __shfl_xor(a2, off, 64);
    }
    __shared__ float red[4][3];
    if ((tid & 63) == 0) {
        red[tid >> 6][0] = a0; red[tid >> 6][1] = a1; red[tid >> 6][2] = a2;
    }
    __syncthreads();
    if (tid < 3) {
        float s = red[0][tid] + red[1][tid] + red[2][tid] + red[3][tid];
        out[(size_t)row * 3 + tid] = s + b2[tid];
    }
}

// ---------------------------------------------------------------------------
extern "C" void kernel_launch(void* const* d_in, const int* in_sizes, int n_in,
                              void* d_out, int out_size, void* d_ws, size_t ws_size,
                              hipStream_t stream) {
    const int*   x      = (const int*)d_in[0];
    const int*   tstart = (const int*)d_in[1];
    const int*   tend   = (const int*)d_in[2];
    const float* emb    = (const float*)d_in[3];
    const float* Wihf   = (const float*)d_in[4];
    const float* Whhf   = (const float*)d_in[5];
    const float* bihf   = (const float*)d_in[6];
    const float* bhhf   = (const float*)d_in[7];
    const float* Wihb   = (const float*)d_in[8];
    const float* Whhb   = (const float*)d_in[9];
    const float* bihb   = (const float*)d_in[10];
    const float* bhhb   = (const float*)d_in[11];
    const float* W1     = (const float*)d_in[12];
    const float* b1     = (const float*)d_in[13];
    const float* u      = (const float*)d_in[14];
    const float* W2     = (const float*)d_in[15];
    const float* b2     = (const float*)d_in[16];
    float* out = (float*)d_out;
    float* ws = (float*)d_ws;

    // workspace layout (floats).  total = 43,236,512 floats = 172.9 MB
    float* h_p    = ws;                        // 16,777,216
    float* e_p    = h_p + 16777216;            // 4,980,736  (16384 x 304)
    float* xwc0_p = e_p + 4980736;             // 6,291,456  (chunk, dir0)
    float* xwc1_p = xwc0_p + 6291456;          // 6,291,456  (chunk, dir1)
    float* Wq_p   = xwc1_p + 6291456;          // 1,572,864  (packed Whh, 2 dirs)
    float* Wt0_p  = Wq_p + 1572864;            // 466,944    (304 x 1536)
    float* Wt1_p  = Wt0_p + 466944;            // 466,944
    float* pad_p  = Wt1_p + 466944;            // 1,700,000  (res alias headroom)
    float* bc0_p  = pad_p + 1700000;           // 1,536
    float* bc1_p  = bc0_p + 1536;              // 1,536
    float* W1at_p = bc1_p + 1536;              // 262,144
    float* tg_p   = W1at_p + 262144;           // 65,536
    float* t2_p   = tg_p + 65536;              // 16,384
    float* beta_p = t2_p + 16384;              // 4,194,304
    float* hx_p   = beta_p + 4194304;          // 131,072
    unsigned* flg_p = (unsigned*)(hx_p + 131072);  // 16,384 uints
    // aliases into dead-after-GRU regions:
    float* ot_p   = e_p;                       // 4,194,304 <= 4,980,736
    float* res_p  = xwc0_p;                    // 16,777,216 <= xwc0..pad (16,789,664)

    if (ws_size < (size_t)43236512 * 4) return;  // refuse to overflow scratch

    // 0. zero pair flags (every call / graph replay)
    hipMemsetAsync(flg_p, 0, 16384 * sizeof(unsigned), stream);
    // 1. embedding + renorm (padded to 304 cols)
    k_embed<<<BS_, 128, 0, stream>>>(x, emb, e_p);
    // 2. one-time weight preps
    k_prep_w1<<<256, 256, 0, stream>>>(W1, W1at_p);
    k_prep_dir<<<512, 256, 0, stream>>>(Wihf, bihf, Wt0_p, bc0_p);
    k_prep_dir<<<512, 256, 0, stream>>>(Wihb, bihb, Wt1_p, bc1_p);
    k_pack_whh2<<<512, 256, 0, stream>>>(Whhf, Wq_p);
    k_pack_whh2<<<512, 256, 0, stream>>>(Whhb, Wq_p + 786432);
    // 3. chunked: project both dirs' 64-pos windows, then pair-split GRU
    for (int c = 0; c < NCHK; ++c) {
        k_gemm128<16, 1><<<dim3(12, 32, 1), 256, 0, stream>>>(
            e_p, EDP, 0, Wt0_p, G3, 0, xwc0_p, G3, 0, BB * CHK, G3, EDP,
            bc0_p, nullptr, CHK * c);
        k_gemm128<16, 1><<<dim3(12, 32, 1), 256, 0, stream>>>(
            e_p, EDP, 0, Wt1_p, G3, 0, xwc1_p, G3, 0, BB * CHK, G3, EDP,
            bc1_p, nullptr, 192 - CHK * c);
        k_gru_pair<<<256, 768, 0, stream>>>(xwc0_p, xwc1_p, Wq_p, bhhf, bhhb,
                                            h_p, hx_p, flg_p, c);
    }
    // 4. target span mean
    k_target<<<BB, 256, 0, stream>>>(h_p, tstart, tend, tg_p);
    // 5. tmp2[b,a] = b1 + target . W1[:,1024:]
    k_tmp2<<<BB, 256, 0, stream>>>(tg_p, W1, b1, t2_p);
    // 6. o = tanh(h @ W1a^T + tmp2)   [16384, 256]  (o at res_p temporarily)
    k_gemm128<16, 2><<<dim3(2, 128, 1), 256, 0, stream>>>(
        h_p, 1024, 0, W1at_p, ATT_, 0, res_p, ATT_, 0, BS_, ATT_, 1024,
        nullptr, t2_p, -1);
    // 7. transpose o -> ot[b][a][s]
    k_transpose_o<<<dim3(8, 8, BB), 256, 0, stream>>>(res_p, ot_p);
    // 8. beta[b][k][s] = u @ ot[b]
    k_gemm128<16, 0><<<dim3(2, 2, BB), 256, 0, stream>>>(
        u, ATT_, 0, ot_p, ATT_, 65536, beta_p, ATT_, 65536, ATT_, ATT_, ATT_,
        nullptr, nullptr, -1);
    // 9. softmax over s (in place)
    k_softmax<<<BS_, 256, 0, stream>>>(beta_p);
    // 10. result[b][k][h] = alfa[b] @ h[b]
    k_gemm128<16, 0><<<dim3(8, 2, BB), 256, 0, stream>>>(
        beta_p, ATT_, 65536, h_p, 1024, 262144, res_p, 1024, 262144,
        ATT_, 1024, ATT_, nullptr, nullptr, -1);
    // 11. final linear
    k_final<<<BS_, 256, 0, stream>>>(res_p, W2, b2, out);
}

// Round 10
// 4574.613 us; speedup vs baseline: 5.0538x; 1.2340x over previous
//
#include <hip/hip_runtime.h>
#include <math.h>

// Problem constants
#define BB   64
#define SS   256
#define ED   300
#define EDP  304    // padded K for input projection (zeros in 300..303)
#define HH   512
#define G3   1536   // 3*H (one direction)
#define ATT_ 256
#define BS_  16384  // BB*SS
#define CHK  64     // timesteps per chunk
#define NCHK 4

// ---------------------------------------------------------------------------
// K1: embedding gather + max-norm renorm.  one block per (b,s) row, 128 thr.
// Writes padded rows of EDP (cols 300..303 = 0) every call (poison-safe).
// ---------------------------------------------------------------------------
__global__ void k_embed(const int* __restrict__ x, const float* __restrict__ emb,
                        float* __restrict__ e) {
    int row = blockIdx.x;
    int tok = x[row];
    const float* src = emb + (size_t)tok * ED;
    float* dst = e + (size_t)row * EDP;
    int tid = threadIdx.x;  // 128
    float v[3];
    float ss = 0.f;
#pragma unroll
    for (int i = 0; i < 3; ++i) {
        int k = tid + i * 128;
        float t = (k < ED) ? src[k] : 0.f;
        v[i] = t;
        ss += t * t;
    }
    for (int off = 32; off > 0; off >>= 1) ss += __shfl_xor(ss, off, 64);
    __shared__ float red[2];
    if ((tid & 63) == 0) red[tid >> 6] = ss;
    __syncthreads();
    float nrm = sqrtf(red[0] + red[1]);
    float scale = fminf(1.0f, 5.0f / (nrm + 1e-7f));
#pragma unroll
    for (int i = 0; i < 3; ++i) {
        int k = tid + i * 128;
        if (k < EDP) dst[k] = (k < ED) ? v[i] * scale : 0.f;
    }
}

// ---------------------------------------------------------------------------
// K_prep_dir: Wt[EDP][1536] = Wih_dir^T (rows 300..303 zero), bc = bih_dir
// ---------------------------------------------------------------------------
__global__ void k_prep_dir(const float* __restrict__ Wih, const float* __restrict__ bih,
                           float* __restrict__ Wt, float* __restrict__ bc) {
    int idx = blockIdx.x * blockDim.x + threadIdx.x;
    int stride = gridDim.x * blockDim.x;
    for (int i = idx; i < ED * G3; i += stride) {
        int n = i / ED, k = i - n * ED;
        Wt[(size_t)k * G3 + n] = Wih[i];
    }
    for (int i = idx; i < 4 * G3; i += stride)
        Wt[(size_t)(ED + i / G3) * G3 + (i % G3)] = 0.f;
    for (int i = idx; i < G3; i += stride) bc[i] = bih[i];
}

// K_prep_w1: W1at[1024][256] = transpose of W1[:, :1024]  (coalesced reads)
__global__ void k_prep_w1(const float* __restrict__ W1, float* __restrict__ W1at) {
    int idx = blockIdx.x * blockDim.x + threadIdx.x;
    int stride = gridDim.x * blockDim.x;
    for (int i = idx; i < 1024 * ATT_; i += stride) {
        int n = i >> 10, k = i & 1023;
        W1at[(size_t)k * ATT_ + n] = W1[(size_t)n * 2048 + k];
    }
}

// ---------------------------------------------------------------------------
// K_pack_whh4: pack one dir's Whh into quarter-split iteration-ordered layout.
// Per-dir flat: [q][m 0..63][t 0..767][e 0..3]  (786,432 floats)
// thread t = 2r + kh; r = gate g*128 + ul; unit u = q*128 + ul;
// k-quad at iteration m: kq = (q*32 + 2m + kh) & 127  (own units' k first).
// ---------------------------------------------------------------------------
__global__ void k_pack_whh4(const float* __restrict__ Whh, float* __restrict__ Wq) {
    int idx = blockIdx.x * blockDim.x + threadIdx.x;
    int stride = gridDim.x * blockDim.x;
    for (int i = idx; i < 4 * 64 * 768 * 4; i += stride) {
        int q   = i / 196608;
        int rem = i - q * 196608;
        int m   = rem / 3072;
        int r2  = rem - m * 3072;
        int t   = r2 >> 2;
        int e   = r2 & 3;
        int r   = t >> 1;
        int kh  = t & 1;
        int g   = r >> 7;
        int ul  = r & 127;
        int u   = q * 128 + ul;
        int kq  = (q * 32 + 2 * m + kh) & 127;
        Wq[i] = Whh[((size_t)(g * 512 + u)) * 512 + kq * 4 + e];
    }
}

// ---------------------------------------------------------------------------
// fp32 GEMM, 128x128 tile, 256 threads, 8x8 per thread, float4 LDS reads.
// spos >= 0: A-row r maps to source row (r/64)*256 + spos + (r%64)
// EPI: 0 = none, 1 = +bias[n], 2 = tanh(acc + bias2[(row>>8)*256 + n])
// ---------------------------------------------------------------------------
#define BSKEW(n) ((n) + (((n) >> 5) << 2))

template <int KT, int EPI>
__global__ void __launch_bounds__(256) k_gemm128(
    const float* __restrict__ A, int lda, long strideA,
    const float* __restrict__ Bm, int ldb, long strideB,
    float* __restrict__ C, int ldc, long strideC,
    int M, int N, int K,
    const float* __restrict__ bias, const float* __restrict__ bias2,
    int spos) {
    __shared__ float As[KT * 132];
    __shared__ float Bs[KT * 144];
    const int tid = threadIdx.x;
    const int tx = tid & 15, ty = tid >> 4;
    const int mbase = blockIdx.y * 128, nbase = blockIdx.x * 128;
    const float* Ab = A + (long)blockIdx.z * strideA;
    const float* Bb = Bm + (long)blockIdx.z * strideB;
    float* Cb = C + (long)blockIdx.z * strideC;
    float acc[8][8] = {};
    const int bgrp = tx * 8 + ((tx >> 2) << 2);
    for (int k0 = 0; k0 < K; k0 += KT) {
        for (int i = tid; i < 128 * KT; i += 256) {
            int r = i / KT, c = i % KT;
            int row = mbase + r;
            int arow = (spos >= 0) ? ((row >> 6) * 256 + spos + (row & 63)) : row;
            As[c * 132 + r] = Ab[(size_t)arow * lda + k0 + c];
        }
        for (int i = tid; i < KT * 128; i += 256) {
            int kk = i >> 7, n = i & 127;
            Bs[kk * 144 + BSKEW(n)] = Bb[(size_t)(k0 + kk) * ldb + nbase + n];
        }
        __syncthreads();
#pragma unroll
        for (int kk = 0; kk < KT; ++kk) {
            const float4* pa = (const float4*)&As[kk * 132 + ty * 8];
            float4 a0 = pa[0], a1 = pa[1];
            const float4* pb = (const float4*)&Bs[kk * 144 + bgrp];
            float4 b0 = pb[0], b1 = pb[1];
            float av[8] = {a0.x, a0.y, a0.z, a0.w, a1.x, a1.y, a1.z, a1.w};
            float bv[8] = {b0.x, b0.y, b0.z, b0.w, b1.x, b1.y, b1.z, b1.w};
#pragma unroll
            for (int i = 0; i < 8; ++i)
#pragma unroll
                for (int j = 0; j < 8; ++j) acc[i][j] += av[i] * bv[j];
        }
        __syncthreads();
    }
#pragma unroll
    for (int i = 0; i < 8; ++i) {
        int row = mbase + ty * 8 + i;
        float vout[8];
#pragma unroll
        for (int j = 0; j < 8; ++j) {
            int col = nbase + tx * 8 + j;
            float v = acc[i][j];
            if (EPI == 1) v += bias[col];
            if (EPI == 2) v = tanhf(v + bias2[(size_t)(row >> 8) * ATT_ + col]);
            vout[j] = v;
        }
        float4* cp = (float4*)&Cb[(size_t)row * ldc + nbase + tx * 8];
        cp[0] = make_float4(vout[0], vout[1], vout[2], vout[3]);
        cp[1] = make_float4(vout[4], vout[5], vout[6], vout[7]);
    }
}

// ---------------------------------------------------------------------------
// GRU helpers
// ---------------------------------------------------------------------------
__device__ __forceinline__ float sigmoidf_(float v) { return 1.f / (1.f + expf(-v)); }

#define GRU_FMA(mm)                                                         \
    {                                                                       \
        float4 h0 = hs4[kq];                                                \
        float4 h1 = hs4[128 + kq];                                          \
        float4 w = wp[(size_t)(mm) * 768];                                  \
        acc0 += h0.x * w.x + h0.y * w.y + h0.z * w.z + h0.w * w.w;          \
        acc1 += h1.x * w.x + h1.y * w.y + h1.z * w.z + h1.w * w.w;          \
        kq = (kq + 2) & 127;                                                \
    }

// ---------------------------------------------------------------------------
// Quarter-split, 2-batch GRU.  256 blocks = pair(32) x dir(2) x quarter(4);
// bid = pair*8 + dir*4 + q  -> XCD (bid%8) serves ONE (dir,q) weight stream
// (0.75 MB resident in its L2, shared by its 32 blocks).
// Each block: 384 rows (3 gates x own 128 units) x full K=512, for TWO batch
// elements -> 8 FMA per weight quad, 0.75 MB/step (half of round 8).
// 4-way h exchange via relaxed IC atomics + release flags (round-8-validated,
// no acquire anywhere).  Phase A (own-unit k-quads, iteration-ordered pack)
// hides the partner h load latency; deposit + barrier; phase B.
// ---------------------------------------------------------------------------
__global__ void __launch_bounds__(768)
k_gru_quad(const float* __restrict__ xw0, const float* __restrict__ xw1,
           const float* __restrict__ Wq,   // [dir][q][m][t][e]
           const float* __restrict__ bhhf, const float* __restrict__ bhhb,
           float* __restrict__ h_all,
           float* __restrict__ hx,         // [parity][dir][pair][bb][512]
           unsigned* __restrict__ flg,     // ((dir*32+pair)*4+q)*32
           int c) {
    const int bid  = blockIdx.x;
    const int pair = bid >> 3;
    const int dir  = (bid >> 2) & 1;
    const int q    = bid & 3;
    const int tid  = threadIdx.x;
    const float* __restrict__ xwc = dir ? xw1 : xw0;
    const float* __restrict__ bhh = dir ? bhhb : bhhf;
    const float4* __restrict__ wq4 =
        (const float4*)Wq + (size_t)(dir * 4 + q) * 49152;
    const float4* __restrict__ wp = wq4 + tid;
    __shared__ __align__(16) float hs[1024];   // [bb][512]
    __shared__ float gact[768];                // [bb][384]

    // init h state
    if (c == 0) {
        for (int t = tid; t < 1024; t += 768) hs[t] = 0.f;
    } else {
        const int prevpos = dir ? (256 - CHK * c) : (CHK * c - 1);
        for (int t = tid; t < 1024; t += 768) {
            int bb = t >> 9, uu = t & 511;
            hs[t] = h_all[((size_t)(pair * 2 + bb) * 256 + prevpos) * 1024 +
                          dir * 512 + uu];
        }
    }
    // gate-thread constants (tid < 256)
    const int ul  = tid & 127;
    const int bbg = (tid >> 7) & 1;
    const int ug  = q * 128 + ul;
    float b0 = 0.f, b1 = 0.f, b2 = 0.f;
    if (tid < 256) { b0 = bhh[ug]; b1 = bhh[512 + ug]; b2 = bhh[1024 + ug]; }
    // partner-load mapping: 768 values = 2 batches x 384 partner units
    const int plb = (tid >= 384) ? 1 : 0;
    const int pli = tid - plb * 384;
    const int plu = pli + ((pli >= q * 128) ? 128 : 0);
    const int fbase = (dir * 32 + pair) * 4;
    const int fi = (fbase + q) * 32;
    const int kh = tid & 1;
    const int rrow = tid >> 1;
    __syncthreads();
    const float4* __restrict__ hs4 = (const float4*)hs;

    for (int j = 0; j < CHK; ++j) {
        const int gi  = c * CHK + j;
        const int pos = dir ? (255 - gi) : gi;
        // --- poll 3 sibling flags, then issue partner h loads (1/thread) ---
        float ph = 0.f;
        if (j > 0) {
            if (tid == 0) {
#pragma unroll
                for (int s = 1; s < 4; ++s) {
                    const unsigned* f = &flg[(fbase + ((q + s) & 3)) * 32];
                    while (__hip_atomic_load(f, __ATOMIC_RELAXED,
                                             __HIP_MEMORY_SCOPE_AGENT) < (unsigned)gi)
                        __builtin_amdgcn_s_sleep(1);
                }
            }
            __syncthreads();
            ph = __hip_atomic_load(
                &hx[(((size_t)((gi - 1) & 1) * 2 + dir) * 32 + pair) * 1024 +
                    plb * 512 + plu],
                __ATOMIC_RELAXED, __HIP_MEMORY_SCOPE_AGENT);
        }
        // --- xw prefetch for gate threads (independent of h) ---
        float xr = 0.f, xz = 0.f, xn = 0.f;
        if (tid < 256) {
            const int b = pair * 2 + bbg;
            const int crow = b * CHK + (dir ? (CHK - 1 - j) : j);
            const float* __restrict__ xrow = xwc + (size_t)crow * 1536;
            xr = xrow[ug]; xz = xrow[512 + ug]; xn = xrow[1024 + ug];
        }
        // --- matvec: 384 rows x K=512 x 2 batches ---
        if (gi > 0) {
            float acc0 = 0.f, acc1 = 0.f;
            int kq = (q * 32 + kh) & 127;
            if (j > 0) {
#pragma unroll 4
                for (int m = 0; m < 16; ++m) GRU_FMA(m);     // own-unit quads
                hs[plb * 512 + plu] = ph;                    // deposit partner h
                __syncthreads();
#pragma unroll 4
                for (int m = 16; m < 64; ++m) GRU_FMA(m);    // partner quads
            } else {
#pragma unroll 4
                for (int m = 0; m < 64; ++m) GRU_FMA(m);     // hs complete
            }
            acc0 += __shfl_xor(acc0, 1, 64);
            acc1 += __shfl_xor(acc1, 1, 64);
            if (kh == 0) { gact[rrow] = acc0; gact[384 + rrow] = acc1; }
        }
        __syncthreads();
        // --- gate update (tid<256: 2 batches x own 128 units) ---
        if (tid < 256) {
            float hr = (gi > 0) ? gact[bbg * 384 + ul] : 0.f;
            float hz = (gi > 0) ? gact[bbg * 384 + 128 + ul] : 0.f;
            float hn = (gi > 0) ? gact[bbg * 384 + 256 + ul] : 0.f;
            float r = sigmoidf_(xr + b0 + hr);
            float z = sigmoidf_(xz + b1 + hz);
            float n = tanhf(xn + r * (b2 + hn));
            float h = (1.f - z) * n + z * hs[bbg * 512 + ug];
            hs[bbg * 512 + ug] = h;
            const int b = pair * 2 + bbg;
            __hip_atomic_store(&h_all[((size_t)b * 256 + pos) * 1024 +
                                      dir * 512 + ug],
                               h, __ATOMIC_RELAXED, __HIP_MEMORY_SCOPE_AGENT);
            __hip_atomic_store(&hx[(((size_t)(gi & 1) * 2 + dir) * 32 + pair) * 1024 +
                                   bbg * 512 + ug],
                               h, __ATOMIC_RELAXED, __HIP_MEMORY_SCOPE_AGENT);
        }
        __syncthreads();   // hx stores drained before release
        if (tid == 0)
            __hip_atomic_store(&flg[fi], (unsigned)(gi + 1), __ATOMIC_RELEASE,
                               __HIP_MEMORY_SCOPE_AGENT);
    }
}

// ---------------------------------------------------------------------------
// K4: masked mean over target span -> target[b, 1024]
// ---------------------------------------------------------------------------
__global__ void k_target(const float* __restrict__ h_all, const int* __restrict__ ts,
                         const int* __restrict__ te, float* __restrict__ target) {
    int b = blockIdx.x;
    int tid = threadIdx.x;  // 256
    int s0 = ts[b], s1 = te[b];
    float inv = 1.f / (float)(s1 - s0 + 1);
    for (int d = tid; d < 1024; d += 256) {
        float acc = 0.f;
        for (int s = s0; s <= s1; ++s) acc += h_all[((size_t)b * 256 + s) * 1024 + d];
        target[(size_t)b * 1024 + d] = acc * inv;
    }
}

// ---------------------------------------------------------------------------
// K4b: tmp2[b,a] = b1[a] + target[b,:] . W1[a, 1024:2048]
// ---------------------------------------------------------------------------
__global__ void k_tmp2(const float* __restrict__ target, const float* __restrict__ W1,
                       const float* __restrict__ b1, float* __restrict__ tmp2) {
    int b = blockIdx.x;
    int a = threadIdx.x;  // 256
    __shared__ float tg[1024];
    for (int d = a; d < 1024; d += 256) tg[d] = target[(size_t)b * 1024 + d];
    __syncthreads();
    const float4* wrow = (const float4*)(W1 + (size_t)a * 2048 + 1024);
    const float4* tg4 = (const float4*)tg;
    float acc = b1[a];
    for (int k = 0; k < 256; ++k) {
        float4 w = wrow[k], t = tg4[k];
        acc += w.x * t.x + w.y * t.y + w.z * t.z + w.w * t.w;
    }
    tmp2[(size_t)b * ATT_ + a] = acc;
}

// ---------------------------------------------------------------------------
// transpose o[b][s][a] -> ot[b][a][s]
// ---------------------------------------------------------------------------
__global__ void k_transpose_o(const float* __restrict__ o, float* __restrict__ ot) {
    int b = blockIdx.z;
    __shared__ float t[32][33];
    int a0 = blockIdx.x * 32, s0 = blockIdx.y * 32;
    int tx = threadIdx.x & 31, ty = threadIdx.x >> 5;  // 32x8
    for (int i = ty; i < 32; i += 8)
        t[i][tx] = o[((size_t)b * 256 + s0 + i) * 256 + a0 + tx];
    __syncthreads();
    for (int i = ty; i < 32; i += 8)
        ot[((size_t)b * 256 + a0 + i) * 256 + s0 + tx] = t[tx][i];
}

// ---------------------------------------------------------------------------
// softmax over last axis, in place.  one block per (b,k) row of 256.
// ---------------------------------------------------------------------------
__global__ void k_softmax(float* __restrict__ beta) {
    int row = blockIdx.x;
    float* p = beta + (size_t)row * 256;
    int tid = threadIdx.x;  // 256
    float v = p[tid];
    float m = v;
    for (int off = 32; off > 0; off >>= 1) m = fmaxf(m, __shfl_xor(m, off, 64));
    __shared__ float red[4];
    if ((tid & 63) == 0) red[tid >> 6] = m;
    __syncthreads();
    m = fmaxf(fmaxf(red[0], red[1]), fmaxf(red[2], red[3]));
    float e = expf(v - m);
    float ssum = e;
    for (int off = 32; off > 0; off >>= 1) ssum += __shfl_xor(ssum, off, 64);
    __shared__ float red2[4];
    if ((tid & 63) == 0) red2[tid >> 6] = ssum;
    __syncthreads();
    float tot = red2[0] + red2[1] + red2[2] + red2[3];
    p[tid] = e / tot;
}

// ---------------------------------------------------------------------------
// final: out[row, 0:3] = result[row,:] . W2[l,:] + b2[l]
// ---------------------------------------------------------------------------
__global__ void k_final(const float* __restrict__ result, const float* __restrict__ W2,
                        const float* __restrict__ b2, float* __restrict__ out) {
    int row = blockIdx.x;
    int tid = threadIdx.x;  // 256
    const float* r = result + (size_t)row * 1024;
    float a0 = 0.f, a1 = 0.f, a2 = 0.f;
    for (int h = tid; h < 1024; h += 256) {
        float rv = r[h];
        a0 += rv * W2[h];
        a1 += rv * W2[1024 + h];
        a2 += rv * W2[2048 + h];
    }
    for (int off = 32; off > 0; off >>= 1) {
        a0 += __shfl_xor(a0, off, 64);
        a1 += __shfl_xor(a1, off, 64);
        a2 += __shfl_xor(a2, off, 64);
    }
    __shared__ float red[4][3];
    if ((tid & 63) == 0) {
        red[tid >> 6][0] = a0; red[tid >> 6][1] = a1; red[tid >> 6][2] = a2;
    }
    __syncthreads();
    if (tid < 3) {
        float s = red[0][tid] + red[1][tid] + red[2][tid] + red[3][tid];
        out[(size_t)row * 3 + tid] = s + b2[tid];
    }
}

// ---------------------------------------------------------------------------
extern "C" void kernel_launch(void* const* d_in, const int* in_sizes, int n_in,
                              void* d_out, int out_size, void* d_ws, size_t ws_size,
                              hipStream_t stream) {
    const int*   x      = (const int*)d_in[0];
    const int*   tstart = (const int*)d_in[1];
    const int*   tend   = (const int*)d_in[2];
    const float* emb    = (const float*)d_in[3];
    const float* Wihf   = (const float*)d_in[4];
    const float* Whhf   = (const float*)d_in[5];
    const float* bihf   = (const float*)d_in[6];
    const float* bhhf   = (const float*)d_in[7];
    const float* Wihb   = (const float*)d_in[8];
    const float* Whhb   = (const float*)d_in[9];
    const float* bihb   = (const float*)d_in[10];
    const float* bhhb   = (const float*)d_in[11];
    const float* W1     = (const float*)d_in[12];
    const float* b1     = (const float*)d_in[13];
    const float* u      = (const float*)d_in[14];
    const float* W2     = (const float*)d_in[15];
    const float* b2     = (const float*)d_in[16];
    float* out = (float*)d_out;
    float* ws = (float*)d_ws;

    // workspace layout (floats).  total = 43,236,512 floats = 172.9 MB
    float* h_p    = ws;                        // 16,777,216
    float* e_p    = h_p + 16777216;            // 4,980,736  (16384 x 304)
    float* xwc0_p = e_p + 4980736;             // 6,291,456  (chunk, dir0)
    float* xwc1_p = xwc0_p + 6291456;          // 6,291,456  (chunk, dir1)
    float* Wq_p   = xwc1_p + 6291456;          // 1,572,864  (packed Whh, 2 dirs)
    float* Wt0_p  = Wq_p + 1572864;            // 466,944    (304 x 1536)
    float* Wt1_p  = Wt0_p + 466944;            // 466,944
    float* pad_p  = Wt1_p + 466944;            // 1,700,000  (res alias headroom)
    float* bc0_p  = pad_p + 1700000;           // 1,536
    float* bc1_p  = bc0_p + 1536;              // 1,536
    float* W1at_p = bc1_p + 1536;              // 262,144
    float* tg_p   = W1at_p + 262144;           // 65,536
    float* t2_p   = tg_p + 65536;              // 16,384
    float* beta_p = t2_p + 16384;              // 4,194,304
    float* hx_p   = beta_p + 4194304;          // 131,072
    unsigned* flg_p = (unsigned*)(hx_p + 131072);  // 16,384 uints
    // aliases into dead-after-GRU regions:
    float* ot_p   = e_p;                       // 4,194,304 <= 4,980,736
    float* res_p  = xwc0_p;                    // 16,777,216 <= xwc0..pad

    if (ws_size < (size_t)43236512 * 4) return;  // refuse to overflow scratch

    // 0. zero pair flags (every call / graph replay)
    hipMemsetAsync(flg_p, 0, 16384 * sizeof(unsigned), stream);
    // 1. embedding + renorm (padded to 304 cols)
    k_embed<<<BS_, 128, 0, stream>>>(x, emb, e_p);
    // 2. one-time weight preps
    k_prep_w1<<<256, 256, 0, stream>>>(W1, W1at_p);
    k_prep_dir<<<512, 256, 0, stream>>>(Wihf, bihf, Wt0_p, bc0_p);
    k_prep_dir<<<512, 256, 0, stream>>>(Wihb, bihb, Wt1_p, bc1_p);
    k_pack_whh4<<<512, 256, 0, stream>>>(Whhf, Wq_p);
    k_pack_whh4<<<512, 256, 0, stream>>>(Whhb, Wq_p + 786432);
    // 3. chunked: project both dirs' 64-pos windows, then quarter-split GRU
    for (int c = 0; c < NCHK; ++c) {
        k_gemm128<16, 1><<<dim3(12, 32, 1), 256, 0, stream>>>(
            e_p, EDP, 0, Wt0_p, G3, 0, xwc0_p, G3, 0, BB * CHK, G3, EDP,
            bc0_p, nullptr, CHK * c);
        k_gemm128<16, 1><<<dim3(12, 32, 1), 256, 0, stream>>>(
            e_p, EDP, 0, Wt1_p, G3, 0, xwc1_p, G3, 0, BB * CHK, G3, EDP,
            bc1_p, nullptr, 192 - CHK * c);
        k_gru_quad<<<256, 768, 0, stream>>>(xwc0_p, xwc1_p, Wq_p, bhhf, bhhb,
                                            h_p, hx_p, flg_p, c);
    }
    // 4. target span mean
    k_target<<<BB, 256, 0, stream>>>(h_p, tstart, tend, tg_p);
    // 5. tmp2[b,a] = b1 + target . W1[:,1024:]
    k_tmp2<<<BB, 256, 0, stream>>>(tg_p, W1, b1, t2_p);
    // 6. o = tanh(h @ W1a^T + tmp2)   [16384, 256]  (o at res_p temporarily)
    k_gemm128<16, 2><<<dim3(2, 128, 1), 256, 0, stream>>>(
        h_p, 1024, 0, W1at_p, ATT_, 0, res_p, ATT_, 0, BS_, ATT_, 1024,
        nullptr, t2_p, -1);
    // 7. transpose o -> ot[b][a][s]
    k_transpose_o<<<dim3(8, 8, BB), 256, 0, stream>>>(res_p, ot_p);
    // 8. beta[b][k][s] = u @ ot[b]
    k_gemm128<16, 0><<<dim3(2, 2, BB), 256, 0, stream>>>(
        u, ATT_, 0, ot_p, ATT_, 65536, beta_p, ATT_, 65536, ATT_, ATT_, ATT_,
        nullptr, nullptr, -1);
    // 9. softmax over s (in place)
    k_softmax<<<BS_, 256, 0, stream>>>(beta_p);
    // 10. result[b][k][h] = alfa[b] @ h[b]
    k_gemm128<16, 0><<<dim3(8, 2, BB), 256, 0, stream>>>(
        beta_p, ATT_, 65536, h_p, 1024, 262144, res_p, 1024, 262144,
        ATT_, 1024, ATT_, nullptr, nullptr, -1);
    // 11. final linear
    k_final<<<BS_, 256, 0, stream>>>(res_p, W2, b2, out);
}